// Round 1
// baseline (4002.668 us; speedup 1.0000x reference)
//
#include <hip/hip_runtime.h>

#define DEV __device__ __forceinline__

// ---------------- block reduce helpers (blockDim == 256) ----------------
DEV float bsum(float v, float* red) {
#pragma unroll
  for (int off = 32; off; off >>= 1) v += __shfl_down(v, off, 64);
  int tid = threadIdx.x;
  __syncthreads();
  if ((tid & 63) == 0) red[tid >> 6] = v;
  __syncthreads();
  return red[0] + red[1] + red[2] + red[3];
}

DEV float bmax(float v, float* red) {
#pragma unroll
  for (int off = 32; off; off >>= 1) v = fmaxf(v, __shfl_down(v, off, 64));
  int tid = threadIdx.x;
  __syncthreads();
  if ((tid & 63) == 0) red[tid >> 6] = v;
  __syncthreads();
  return fmaxf(fmaxf(red[0], red[1]), fmaxf(red[2], red[3]));
}

DEV float sigmoidf(float x) { return 1.f / (1.f + expf(-x)); }

// ---------------- adaptive adjacency: a = (softmax(relu(nv1@nv2)) + I)/2 ----
// one block per row v (512 blocks x 256 threads)
__global__ __launch_bounds__(256) void k_adj(const float* __restrict__ nv1,
                                             const float* __restrict__ nv2,
                                             float* __restrict__ a) {
  const int v = blockIdx.x, tid = threadIdx.x;
  __shared__ float n1[32];
  __shared__ float red[4];
  if (tid < 32) n1[tid] = nv1[v * 32 + tid];
  __syncthreads();
  float r0, r1;
  {
    int w = tid;
    float s = 0.f;
#pragma unroll 8
    for (int k = 0; k < 32; ++k) s += n1[k] * nv2[k * 512 + w];
    r0 = fmaxf(s, 0.f);
  }
  {
    int w = tid + 256;
    float s = 0.f;
#pragma unroll 8
    for (int k = 0; k < 32; ++k) s += n1[k] * nv2[k * 512 + w];
    r1 = fmaxf(s, 0.f);
  }
  float mx = bmax(fmaxf(r0, r1), red);
  float e0 = expf(r0 - mx), e1 = expf(r1 - mx);
  float s = bsum(e0 + e1, red);
  float inv = 1.f / s;
  int w0 = tid, w1 = tid + 256;
  a[(long)v * 512 + w0] = (e0 * inv + (w0 == v ? 1.f : 0.f)) * 0.5f;
  a[(long)v * 512 + w1] = (e1 * inv + (w1 == v ? 1.f : 0.f)) * 0.5f;
}

// ---------------- fold start_conv + mixprop + 1x1 mlp into 3 coef vectors ---
__global__ void k_coef(const float* __restrict__ mp_w, const float* __restrict__ mp_b,
                       const float* __restrict__ sc_w, const float* __restrict__ sc_b,
                       float* __restrict__ cf) {
  int o = threadIdx.x;
  if (o < 32) {
    float A = 0.f, Bv = 0.f, Cv = 0.f;
    for (int cc = 0; cc < 32; ++cc) {
      float m1 = mp_w[o * 64 + cc], m2 = mp_w[o * 64 + 32 + cc];
      float sw = sc_w[cc], sb = sc_b[cc];
      A += (m1 + 0.7f * m2) * sw;
      Bv += 0.3f * m2 * sw;
      Cv += (m1 + m2) * sb;
    }
    cf[o] = A;
    cf[32 + o] = Bv;
    cf[64 + o] = Cv + mp_b[o];
  }
}

// ---------------- generic f32 NT GEMM: C[m,n] = sum_k A[m,k]B[n,k] (+dual) --
// BM=128, BN=64, BK=16, 256 threads, 8x4 microtile. grid.z batches via strides.
__global__ __launch_bounds__(256) void k_gemm(
    const float* __restrict__ A, long lda, long sAz,
    const float* __restrict__ B, long ldb, long sBz,
    const float* __restrict__ A2, long lda2, long sA2z,
    const float* __restrict__ B2, long ldb2, long sB2z,
    const float* __restrict__ bias,
    float* __restrict__ C, long ldc, long sCz,
    int K, int dual) {
  __shared__ float As[16][128];
  __shared__ float Bs[16][64];
  const int tid = threadIdx.x;
  const int bm = blockIdx.x, bn = blockIdx.y, z = blockIdx.z;
  A += (long)z * sAz;
  B += (long)z * sBz;
  C += (long)z * sCz;
  A2 += (long)z * sA2z;
  B2 += (long)z * sB2z;
  const int tx = tid & 15, ty = tid >> 4;
  float acc[8][4];
#pragma unroll
  for (int i = 0; i < 8; ++i)
#pragma unroll
    for (int j = 0; j < 4; ++j) acc[i][j] = 0.f;

  const int ra = tid >> 1;        // 0..127
  const int ka = (tid & 1) * 8;   // 0 / 8
  const int rb = tid >> 2;        // 0..63
  const int kb = (tid & 3) * 4;   // 0,4,8,12

  const int nsrc = dual ? 2 : 1;
  for (int src = 0; src < nsrc; ++src) {
    const float* Ap = src ? A2 : A;
    const float* Bp = src ? B2 : B;
    const long ldA = src ? lda2 : lda;
    const long ldB = src ? ldb2 : ldb;
    const float* arow = Ap + (long)(bm * 128 + ra) * ldA + ka;
    const float* brow = Bp + (long)(bn * 64 + rb) * ldB + kb;
    for (int k0 = 0; k0 < K; k0 += 16) {
      __syncthreads();
      float4 av0 = *(const float4*)(arow + k0);
      float4 av1 = *(const float4*)(arow + k0 + 4);
      float4 bv = *(const float4*)(brow + k0);
      As[ka + 0][ra] = av0.x;
      As[ka + 1][ra] = av0.y;
      As[ka + 2][ra] = av0.z;
      As[ka + 3][ra] = av0.w;
      As[ka + 4][ra] = av1.x;
      As[ka + 5][ra] = av1.y;
      As[ka + 6][ra] = av1.z;
      As[ka + 7][ra] = av1.w;
      Bs[kb + 0][rb] = bv.x;
      Bs[kb + 1][rb] = bv.y;
      Bs[kb + 2][rb] = bv.z;
      Bs[kb + 3][rb] = bv.w;
      __syncthreads();
#pragma unroll
      for (int kk = 0; kk < 16; ++kk) {
        const float4 a0 = *(const float4*)&As[kk][ty * 8];
        const float4 a1 = *(const float4*)&As[kk][ty * 8 + 4];
        const float4 b4 = *(const float4*)&Bs[kk][tx * 4];
        const float am[8] = {a0.x, a0.y, a0.z, a0.w, a1.x, a1.y, a1.z, a1.w};
        const float bm_[4] = {b4.x, b4.y, b4.z, b4.w};
#pragma unroll
        for (int i = 0; i < 8; ++i)
#pragma unroll
          for (int j = 0; j < 4; ++j) acc[i][j] = fmaf(am[i], bm_[j], acc[i][j]);
      }
    }
  }
  const long crow = (long)(bm * 128 + ty * 8);
  const int cn = bn * 64 + tx * 4;
  float b0 = 0.f, b1 = 0.f, b2 = 0.f, b3 = 0.f;
  if (bias) {
    b0 = bias[cn + 0];
    b1 = bias[cn + 1];
    b2 = bias[cn + 2];
    b3 = bias[cn + 3];
  }
#pragma unroll
  for (int i = 0; i < 8; ++i) {
    float4 cv;
    cv.x = acc[i][0] + b0;
    cv.y = acc[i][1] + b1;
    cv.z = acc[i][2] + b2;
    cv.w = acc[i][3] + b3;
    *(float4*)&C[(crow + i) * ldc + cn] = cv;
  }
}

// ---------------- fused gelu(A*x+B*y+C) -> end_conv einsum ------------------
// grid (1024, 2), 256 thr: one (b, v) pair per thread
__global__ __launch_bounds__(256) void k_oe(const float* __restrict__ x,
                                            const float* __restrict__ yg,
                                            const float* __restrict__ cf,
                                            const float* __restrict__ ec_w,
                                            const float* __restrict__ ec_b,
                                            float* __restrict__ oe) {
  const int b = blockIdx.x;
  const int v = blockIdx.y * 256 + threadIdx.x;
  __shared__ float ecs[512];
  __shared__ float cfs[96];
  __shared__ float ebs[4];
  if (threadIdx.x < 96) cfs[threadIdx.x] = cf[threadIdx.x];
  if (threadIdx.x < 4) ebs[threadIdx.x] = ec_b[threadIdx.x];
  for (int i = threadIdx.x; i < 512; i += 256) ecs[i] = ec_w[i];
  __syncthreads();
  float xl[4], yl[4];
#pragma unroll
  for (int l = 0; l < 4; ++l) {
    long off = ((long)b * 4 + l) * 512 + v;
    xl[l] = x[off];
    yl[l] = yg[off];
  }
  float o0 = ebs[0], o1 = ebs[1], o2 = ebs[2], o3 = ebs[3];
  for (int cc = 0; cc < 32; ++cc) {
    float A = cfs[cc], Bv = cfs[32 + cc], Cv = cfs[64 + cc];
#pragma unroll
    for (int l = 0; l < 4; ++l) {
      float u = fmaf(A, xl[l], fmaf(Bv, yl[l], Cv));
      float gu = 0.5f * u * (1.f + erff(u * 0.70710678118654752f));
      o0 = fmaf(ecs[(0 * 32 + cc) * 4 + l], gu, o0);
      o1 = fmaf(ecs[(1 * 32 + cc) * 4 + l], gu, o1);
      o2 = fmaf(ecs[(2 * 32 + cc) * 4 + l], gu, o2);
      o3 = fmaf(ecs[(3 * 32 + cc) * 4 + l], gu, o3);
    }
  }
  oe[((long)b * 4 + 0) * 512 + v] = o0;
  oe[((long)b * 4 + 1) * 512 + v] = o1;
  oe[((long)b * 4 + 2) * 512 + v] = o2;
  oe[((long)b * 4 + 3) * 512 + v] = o3;
}

// ---------------- LN(x+g) then softmax -> xg, gw (width 512) ----------------
__global__ __launch_bounds__(256) void k_lngw(const float* __restrict__ x,
                                              const float* __restrict__ g,
                                              const float* __restrict__ gg,
                                              const float* __restrict__ gb,
                                              float* __restrict__ xg,
                                              float* __restrict__ gw) {
  const long r = blockIdx.x;
  const int tid = threadIdx.x;
  __shared__ float red[4];
  const float* xp = x + r * 512;
  const float* gp = g + r * 512;
  float a0 = xp[tid] + gp[tid];
  float a1 = xp[tid + 256] + gp[tid + 256];
  float m = bsum(a0 + a1, red) * (1.f / 512.f);
  float q = (a0 - m) * (a0 - m) + (a1 - m) * (a1 - m);
  float var = bsum(q, red) * (1.f / 512.f);
  float rstd = rsqrtf(var + 1e-5f);
  float v0 = (a0 - m) * rstd * gg[tid] + gb[tid];
  float v1 = (a1 - m) * rstd * gg[tid + 256] + gb[tid + 256];
  xg[r * 512 + tid] = v0;
  xg[r * 512 + tid + 256] = v1;
  float mx = bmax(fmaxf(v0, v1), red);
  float e0 = expf(v0 - mx), e1 = expf(v1 - mx);
  float s = bsum(e0 + e1, red);
  float inv = 1.f / s;
  gw[r * 512 + tid] = e0 * inv;
  gw[r * 512 + tid + 256] = e1 * inv;
}

// ---------------- LSTM gate pointwise -------------------------------------
// grid (2048, 2): dir = blockIdx.y
__global__ __launch_bounds__(256) void k_gates(
    const float* __restrict__ z, const float* __restrict__ Wb,
    const float* __restrict__ Ub, const float* __restrict__ gw0,
    const float* __restrict__ gw1, float* __restrict__ h, float* __restrict__ c,
    float* __restrict__ yl, int l, int t) {
  const int dir = blockIdx.y;
  const int idx = blockIdx.x * 256 + threadIdx.x;
  const int b = idx >> 9, o = idx & 511;
  const float* zp = z + (long)dir * (1024L * 2560) + (long)b * 2560 + o;
  const long boff = ((long)(dir * 4 + l) * 5) * 512 + o;
  float zi = zp[0] + Wb[boff] + Ub[boff];
  float zf = zp[512] + Wb[boff + 512] + Ub[boff + 512];
  float zo = zp[1024] + Wb[boff + 1024] + Ub[boff + 1024];
  float zc = zp[1536] + Wb[boff + 1536] + Ub[boff + 1536];
  float zs = zp[2048] + Wb[boff + 2048] + Ub[boff + 2048];
  const float* gwp = dir ? gw1 : gw0;
  float dw = gwp[(long)b * 2048 + o];
  const long hc = ((long)(dir * 4 + l) * 1024 + b) * 512 + o;
  float i_t = sigmoidf(zi), f_t = sigmoidf(zf), o_t = sigmoidf(zo);
  float ch = tanhf(zc);
  float s_t = sigmoidf(zs) * dw;
  float cn = f_t * c[hc] + i_t * ch * s_t;
  float hn = o_t * tanhf(cn);
  c[hc] = cn;
  h[hc] = hn;
  if (l == 3) {
    int tok = dir ? (3 - t) : t;
    yl[(long)b * 4096 + (long)tok * 1024 + dir * 512 + o] = hn;
  }
}

// ---------------- tiny attention (N=4 tokens), block = (b, head) ------------
__global__ __launch_bounds__(256) void k_attn(const float* __restrict__ qkv,
                                              float* __restrict__ out, int d,
                                              float scale) {
  const int b = blockIdx.x, h = blockIdx.y;
  __shared__ float qs[4][256], ks[4][256], vs[4][256];
  __shared__ float sc[4][4];
  const int tid = threadIdx.x;
  for (int tok = 0; tok < 4; ++tok) {
    const float* base = qkv + ((long)b * 4 + tok) * 3072 + h * d;
    for (int j = tid; j < d; j += 256) {
      qs[tok][j] = base[j];
      ks[tok][j] = base[1024 + j];
      vs[tok][j] = base[2048 + j];
    }
  }
  __syncthreads();
  if (tid < 16) {
    int i = tid >> 2, j = tid & 3;
    float s = 0.f;
    for (int dd = 0; dd < d; ++dd) s += qs[i][dd] * ks[j][dd];
    sc[i][j] = s * scale;
  }
  __syncthreads();
  if (tid < 4) {
    float m = fmaxf(fmaxf(sc[tid][0], sc[tid][1]), fmaxf(sc[tid][2], sc[tid][3]));
    float e0 = expf(sc[tid][0] - m), e1 = expf(sc[tid][1] - m);
    float e2 = expf(sc[tid][2] - m), e3 = expf(sc[tid][3] - m);
    float inv = 1.f / (e0 + e1 + e2 + e3);
    sc[tid][0] = e0 * inv;
    sc[tid][1] = e1 * inv;
    sc[tid][2] = e2 * inv;
    sc[tid][3] = e3 * inv;
  }
  __syncthreads();
  for (int idx = tid; idx < 4 * d; idx += 256) {
    int i = idx / d, dd = idx - i * d;
    float o = sc[i][0] * vs[0][dd] + sc[i][1] * vs[1][dd] + sc[i][2] * vs[2][dd] +
              sc[i][3] * vs[3][dd];
    out[((long)b * 4 + i) * 1024 + (long)h * d + dd] = o;
  }
}

// ---------------- LayerNorm width 1024 -------------------------------------
__global__ __launch_bounds__(256) void k_ln1024(const float* __restrict__ in,
                                                const float* __restrict__ gg,
                                                const float* __restrict__ bb,
                                                float* __restrict__ out) {
  const long r = blockIdx.x;
  const int tid = threadIdx.x;
  __shared__ float red[4];
  const float* ip = in + r * 1024;
  float v[4];
#pragma unroll
  for (int i = 0; i < 4; ++i) v[i] = ip[tid + i * 256];
  float m = bsum(v[0] + v[1] + v[2] + v[3], red) * (1.f / 1024.f);
  float q = 0.f;
#pragma unroll
  for (int i = 0; i < 4; ++i) q += (v[i] - m) * (v[i] - m);
  float rstd = rsqrtf(bsum(q, red) * (1.f / 1024.f) + 1e-5f);
  float* op = out + r * 1024;
#pragma unroll
  for (int i = 0; i < 4; ++i) {
    int cidx = tid + i * 256;
    op[cidx] = (v[i] - m) * rstd * gg[cidx] + bb[cidx];
  }
}

// ---------------- DMIN LN + sigmoid gate -----------------------------------
__global__ __launch_bounds__(256) void k_dmin(const float* __restrict__ zin,
                                              const float* __restrict__ ori,
                                              const float* __restrict__ gg,
                                              const float* __restrict__ bb,
                                              float* __restrict__ y2) {
  const long r = blockIdx.x;
  const int tid = threadIdx.x;
  __shared__ float red[4];
  const float* ip = zin + r * 1024;
  float v[4];
#pragma unroll
  for (int i = 0; i < 4; ++i) v[i] = ip[tid + i * 256];
  float m = bsum(v[0] + v[1] + v[2] + v[3], red) * (1.f / 1024.f);
  float q = 0.f;
#pragma unroll
  for (int i = 0; i < 4; ++i) q += (v[i] - m) * (v[i] - m);
  float rstd = rsqrtf(bsum(q, red) * (1.f / 1024.f) + 1e-5f);
#pragma unroll
  for (int i = 0; i < 4; ++i) {
    int cidx = tid + i * 256;
    float ln = (v[i] - m) * rstd * gg[cidx] + bb[cidx];
    y2[r * 1024 + cidx] = ori[r * 1024 + cidx] * sigmoidf(ln);
  }
}

// ---------------- pwconv over feature axis (C=4 bag -> 1, k=3, pad 1) -------
__global__ __launch_bounds__(256) void k_pw(const float* __restrict__ y2,
                                            const float* __restrict__ pw,
                                            const float* __restrict__ pb,
                                            float* __restrict__ xfer) {
  const int b = blockIdx.x;
  __shared__ float w[12];
  if (threadIdx.x < 12) w[threadIdx.x] = pw[threadIdx.x];
  __syncthreads();
  const float bias = pb[0];
  for (int e = threadIdx.x; e < 1024; e += 256) {
    float acc = bias;
#pragma unroll
    for (int c = 0; c < 4; ++c) {
      const float* yr = y2 + (long)b * 4096 + (long)c * 1024;
      if (e > 0) acc = fmaf(yr[e - 1], w[c * 3 + 0], acc);
      acc = fmaf(yr[e], w[c * 3 + 1], acc);
      if (e < 1023) acc = fmaf(yr[e + 1], w[c * 3 + 2], acc);
    }
    xfer[(long)b * 1024 + e] = acc;
  }
}

// ---------------- final fc: [1024] -> [7] ----------------------------------
__global__ __launch_bounds__(256) void k_fc(const float* __restrict__ xf,
                                            const float* __restrict__ fw,
                                            const float* __restrict__ fb,
                                            float* __restrict__ out) {
  const int b = blockIdx.x, tid = threadIdx.x;
  float acc[7] = {0.f, 0.f, 0.f, 0.f, 0.f, 0.f, 0.f};
  for (int e = tid; e < 1024; e += 256) {
    float xv = xf[(long)b * 1024 + e];
#pragma unroll
    for (int j = 0; j < 7; ++j) acc[j] = fmaf(xv, fw[j * 1024 + e], acc[j]);
  }
  __shared__ float red[4][7];
#pragma unroll
  for (int j = 0; j < 7; ++j) {
    float v = acc[j];
#pragma unroll
    for (int off = 32; off; off >>= 1) v += __shfl_down(v, off, 64);
    if ((tid & 63) == 0) red[tid >> 6][j] = v;
  }
  __syncthreads();
  if (tid < 7)
    out[(long)b * 7 + tid] =
        red[0][tid] + red[1][tid] + red[2][tid] + red[3][tid] + fb[tid];
}

// ===========================================================================
extern "C" void kernel_launch(void* const* d_in, const int* in_sizes, int n_in,
                              void* d_out, int out_size, void* d_ws,
                              size_t ws_size, hipStream_t stream) {
  const float* x = (const float*)d_in[0];
  const float* nv1 = (const float*)d_in[1];
  const float* nv2 = (const float*)d_in[2];
  const float* sc_w = (const float*)d_in[3];
  const float* sc_b = (const float*)d_in[4];
  const float* mp_w = (const float*)d_in[5];
  const float* mp_b = (const float*)d_in[6];
  const float* ec_w = (const float*)d_in[7];
  const float* ec_b = (const float*)d_in[8];
  const float* gbl_w = (const float*)d_in[9];
  const float* gbl_b = (const float*)d_in[10];
  const float* gbln_g = (const float*)d_in[11];
  const float* gbln_b = (const float*)d_in[12];
  const float* lstm_W = (const float*)d_in[13];
  const float* lstm_Wb = (const float*)d_in[14];
  const float* lstm_U = (const float*)d_in[15];
  const float* lstm_Ub = (const float*)d_in[16];
  const float* mha_in_w = (const float*)d_in[17];
  const float* mha_in_b = (const float*)d_in[18];
  const float* mha_out_w = (const float*)d_in[19];
  const float* mha_out_b = (const float*)d_in[20];
  const float* ln1_g = (const float*)d_in[21];
  const float* ln1_b = (const float*)d_in[22];
  const float* qkv_w = (const float*)d_in[23];
  const float* dmin_g = (const float*)d_in[24];
  const float* dmin_b = (const float*)d_in[25];
  const float* pw_w = (const float*)d_in[26];
  const float* pw_b = (const float*)d_in[27];
  const float* fc_w = (const float*)d_in[28];
  const float* fc_b = (const float*)d_in[29];

  float* ws = (float*)d_ws;
  float* out = (float*)d_out;
  float* xfer = out + 1024 * 7;

  // workspace layout (floats). post-LSTM buffers alias the graph/LSTM region.
  float* wA = ws + 0;           //   262,144  adjacency a [512][512]
  float* wY = ws + 262144;      // 2,097,152  y_graph, then g
  float* wOE = ws + 2359296;    // 2,097,152  oe
  float* wXG = ws + 4456448;    // 2,097,152  xg
  float* wGW = ws + 6553600;    // 2,097,152  gw
  float* wH = ws + 8650752;     // 4,194,304  h state [2][4][1024][512]
  float* wC = ws + 12845056;    // 4,194,304  c state
  float* wZ = ws + 17039360;    // 5,242,880  z [2][1024][2560]   (ends 22,282,240)
  float* wQKV = ws + 0;         // 12,582,912 (aliases dead graph bufs post-LSTM)
  float* wATT = ws + 12582912;  // 4,194,304
  float* wTMP = ws + 16777216;  // 4,194,304  mha_y, then y2
  float* wYL = ws + 22282240;   // 4,194,304  lstm output y [1024][4][1024]
  float* wORI = ws + 26476544;  // 4,194,304  ori (after ln1)
  float* wCF = ws + 30670848;   //        96  folded mixprop coefs

  // zero LSTM h/c state (contiguous)
  hipMemsetAsync(wH, 0, (size_t)8388608 * sizeof(float), stream);

  // ---- graph block ----
  k_adj<<<512, 256, 0, stream>>>(nv1, nv2, wA);
  k_coef<<<1, 64, 0, stream>>>(mp_w, mp_b, sc_w, sc_b, wCF);
  // y = X @ a^T   (M=4096, N=512, K=512)
  k_gemm<<<dim3(32, 8, 1), 256, 0, stream>>>(x, 512, 0, wA, 512, 0, x, 512, 0,
                                             wA, 512, 0, nullptr, wY, 512, 0,
                                             512, 0);
  k_oe<<<dim3(1024, 2, 1), 256, 0, stream>>>(x, wY, wCF, ec_w, ec_b, wOE);
  // g = oe @ gbl_w^T + gbl_b  (M=4096, N=512, K=512) -> reuse wY
  k_gemm<<<dim3(32, 8, 1), 256, 0, stream>>>(wOE, 512, 0, gbl_w, 512, 0, wOE,
                                             512, 0, gbl_w, 512, 0, gbl_b, wY,
                                             512, 0, 512, 0);
  k_lngw<<<4096, 256, 0, stream>>>(x, wY, gbln_g, gbln_b, wXG, wGW);

  // ---- bidirectional 4-layer LSTM (dirs batched on grid.z) ----
  for (int t = 0; t < 4; ++t) {
    for (int l = 0; l < 4; ++l) {
      const float* A0;
      long lda, sAz;
      if (l == 0) {
        A0 = wXG + (long)t * 512;
        lda = 2048;
        sAz = (long)(3 - 2 * t) * 512;  // dir1 starts at token 3-t
      } else {
        A0 = wH + (long)(l - 1) * 524288;
        lda = 512;
        sAz = 4L * 524288;
      }
      const float* A2 = wH + (long)l * 524288;
      const float* Bw = lstm_W + (long)l * 1310720;
      const float* Bu = lstm_U + (long)l * 1310720;
      // z = x_t @ W^T + h @ U^T   (M=1024, N=2560, K=512 dual)
      k_gemm<<<dim3(8, 40, 2), 256, 0, stream>>>(
          A0, lda, sAz, Bw, 512, 5242880L, A2, 512, 4L * 524288, Bu, 512,
          5242880L, nullptr, wZ, 2560, 2621440L, 512, 1);
      k_gates<<<dim3(2048, 2, 1), 256, 0, stream>>>(
          wZ, lstm_Wb, lstm_Ub, wGW + (long)t * 512, wGW + (long)(3 - t) * 512,
          wH, wC, wYL, l, t);
    }
  }

  // ---- MHA (4 heads, d=256) ----
  k_gemm<<<dim3(32, 48, 1), 256, 0, stream>>>(
      wYL, 1024, 0, mha_in_w, 1024, 0, wYL, 1024, 0, mha_in_w, 1024, 0,
      mha_in_b, wQKV, 3072, 0, 1024, 0);
  k_attn<<<dim3(1024, 4, 1), 256, 0, stream>>>(wQKV, wATT, 256, 1.f / 16.f);
  k_gemm<<<dim3(32, 16, 1), 256, 0, stream>>>(
      wATT, 1024, 0, mha_out_w, 1024, 0, wATT, 1024, 0, mha_out_w, 1024, 0,
      mha_out_b, wTMP, 1024, 0, 1024, 0);
  k_ln1024<<<4096, 256, 0, stream>>>(wTMP, ln1_g, ln1_b, wORI);

  // ---- MIL self-attention fusion (8 heads, d=128) ----
  k_gemm<<<dim3(32, 48, 1), 256, 0, stream>>>(
      wORI, 1024, 0, qkv_w, 1024, 0, wORI, 1024, 0, qkv_w, 1024, 0, nullptr,
      wQKV, 3072, 0, 1024, 0);
  k_attn<<<dim3(1024, 8, 1), 256, 0, stream>>>(wQKV, wATT, 128,
                                               0.08838834764831845f);
  k_dmin<<<4096, 256, 0, stream>>>(wATT, wORI, dmin_g, dmin_b, wTMP);

  // ---- pwconv + fc ----
  k_pw<<<1024, 256, 0, stream>>>(wTMP, pw_w, pw_b, xfer);
  k_fc<<<1024, 256, 0, stream>>>(xfer, fc_w, fc_b, out);
}

// Round 3
// 1732.320 us; speedup vs baseline: 2.3106x; 2.3106x over previous
//
#include <hip/hip_runtime.h>

#define DEV __device__ __forceinline__

typedef __attribute__((ext_vector_type(8))) short bf16x8;
typedef __attribute__((ext_vector_type(4))) float f32x4;

DEV unsigned short f2b(float f) {
  union { float f; unsigned u; } v;
  v.f = f;
  unsigned r = v.u + 0x7FFFu + ((v.u >> 16) & 1u);
  return (unsigned short)(r >> 16);
}

// ---------------- block reduce helpers (blockDim == 256) ----------------
DEV float bsum(float v, float* red) {
#pragma unroll
  for (int off = 32; off; off >>= 1) v += __shfl_down(v, off, 64);
  int tid = threadIdx.x;
  __syncthreads();
  if ((tid & 63) == 0) red[tid >> 6] = v;
  __syncthreads();
  return red[0] + red[1] + red[2] + red[3];
}

DEV float bmax(float v, float* red) {
#pragma unroll
  for (int off = 32; off; off >>= 1) v = fmaxf(v, __shfl_down(v, off, 64));
  int tid = threadIdx.x;
  __syncthreads();
  if ((tid & 63) == 0) red[tid >> 6] = v;
  __syncthreads();
  return fmaxf(fmaxf(red[0], red[1]), fmaxf(red[2], red[3]));
}

DEV float sigmoidf(float x) { return 1.f / (1.f + expf(-x)); }

// ---------------- adaptive adjacency: a = (softmax(relu(nv1@nv2)) + I)/2 ----
__global__ __launch_bounds__(256) void k_adj(const float* __restrict__ nv1,
                                             const float* __restrict__ nv2,
                                             float* __restrict__ a) {
  const int v = blockIdx.x, tid = threadIdx.x;
  __shared__ float n1[32];
  __shared__ float red[4];
  if (tid < 32) n1[tid] = nv1[v * 32 + tid];
  __syncthreads();
  float r0, r1;
  {
    int w = tid;
    float s = 0.f;
#pragma unroll 8
    for (int k = 0; k < 32; ++k) s += n1[k] * nv2[k * 512 + w];
    r0 = fmaxf(s, 0.f);
  }
  {
    int w = tid + 256;
    float s = 0.f;
#pragma unroll 8
    for (int k = 0; k < 32; ++k) s += n1[k] * nv2[k * 512 + w];
    r1 = fmaxf(s, 0.f);
  }
  float mx = bmax(fmaxf(r0, r1), red);
  float e0 = expf(r0 - mx), e1 = expf(r1 - mx);
  float s = bsum(e0 + e1, red);
  float inv = 1.f / s;
  int w0 = tid, w1 = tid + 256;
  a[(long)v * 512 + w0] = (e0 * inv + (w0 == v ? 1.f : 0.f)) * 0.5f;
  a[(long)v * 512 + w1] = (e1 * inv + (w1 == v ? 1.f : 0.f)) * 0.5f;
}

// ---------------- fold start_conv + mixprop + 1x1 mlp into 3 coef vectors ---
__global__ void k_coef(const float* __restrict__ mp_w, const float* __restrict__ mp_b,
                       const float* __restrict__ sc_w, const float* __restrict__ sc_b,
                       float* __restrict__ cf) {
  int o = threadIdx.x;
  if (o < 32) {
    float A = 0.f, Bv = 0.f, Cv = 0.f;
    for (int cc = 0; cc < 32; ++cc) {
      float m1 = mp_w[o * 64 + cc], m2 = mp_w[o * 64 + 32 + cc];
      float sw = sc_w[cc], sb = sc_b[cc];
      A += (m1 + 0.7f * m2) * sw;
      Bv += 0.3f * m2 * sw;
      Cv += (m1 + m2) * sb;
    }
    cf[o] = A;
    cf[32 + o] = Bv;
    cf[64 + o] = Cv + mp_b[o];
  }
}

// ---------------- bf16 MFMA NT GEMM: C[m,n] = sum_k A[m,k]B[n,k] (+dual) ----
// BM=128, BN=128, BK=64, 256 threads = 4 waves (2x2), 4x4 16x16 frags/wave.
// A,B are f32 in global; converted to bf16 during LDS staging. C is f32.
// LDS K-stride padded to 72 bf16 (144B, 16B-aligned, conflict-benign).
__global__ __launch_bounds__(256) void k_mgemm(
    const float* __restrict__ A, long lda, long sAz,
    const float* __restrict__ B, long ldb, long sBz,
    const float* __restrict__ A2, long lda2, long sA2z,
    const float* __restrict__ B2, long ldb2, long sB2z,
    const float* __restrict__ bias,
    float* __restrict__ C, long ldc, long sCz,
    int K, int dual) {
  __shared__ unsigned short As[128 * 72];
  __shared__ unsigned short Bs[128 * 72];
  const int tid = threadIdx.x;
  const int bm = blockIdx.x, bn = blockIdx.y, z = blockIdx.z;
  A += (long)z * sAz;
  B += (long)z * sBz;
  C += (long)z * sCz;
  A2 += (long)z * sA2z;
  B2 += (long)z * sB2z;

  const int lane = tid & 63, wave = tid >> 6;
  const int wr = wave >> 1, wc = wave & 1;     // wave -> 64x64 quadrant
  const int lr = lane & 15, lg = lane >> 4;    // frag row/col, k-group

  f32x4 acc[4][4];
#pragma unroll
  for (int m = 0; m < 4; ++m)
#pragma unroll
    for (int n = 0; n < 4; ++n) acc[m][n] = (f32x4){0.f, 0.f, 0.f, 0.f};

  // staging map: tile 128 rows x 64 cols, thread handles 4 rows x 8-elem chunk
  const int srow = tid >> 3;           // 0..31
  const int skc = (tid & 7) * 8;       // 0,8,..,56

  const int nsrc = dual ? 2 : 1;
  for (int src = 0; src < nsrc; ++src) {
    const float* Ap = src ? A2 : A;
    const float* Bp = src ? B2 : B;
    const long ldA = src ? lda2 : lda;
    const long ldB = src ? ldb2 : ldb;
    for (int k0 = 0; k0 < K; k0 += 64) {
      __syncthreads();
#pragma unroll
      for (int i = 0; i < 4; ++i) {
        const int row = srow + i * 32;
        const float* ga = Ap + (long)(bm * 128 + row) * ldA + k0 + skc;
        float4 a0 = *(const float4*)ga;
        float4 a1 = *(const float4*)(ga + 4);
        bf16x8 pa;
        pa[0] = (short)f2b(a0.x); pa[1] = (short)f2b(a0.y);
        pa[2] = (short)f2b(a0.z); pa[3] = (short)f2b(a0.w);
        pa[4] = (short)f2b(a1.x); pa[5] = (short)f2b(a1.y);
        pa[6] = (short)f2b(a1.z); pa[7] = (short)f2b(a1.w);
        *(bf16x8*)&As[row * 72 + skc] = pa;
        const float* gb = Bp + (long)(bn * 128 + row) * ldB + k0 + skc;
        float4 b0 = *(const float4*)gb;
        float4 b1 = *(const float4*)(gb + 4);
        bf16x8 pb;
        pb[0] = (short)f2b(b0.x); pb[1] = (short)f2b(b0.y);
        pb[2] = (short)f2b(b0.z); pb[3] = (short)f2b(b0.w);
        pb[4] = (short)f2b(b1.x); pb[5] = (short)f2b(b1.y);
        pb[6] = (short)f2b(b1.z); pb[7] = (short)f2b(b1.w);
        *(bf16x8*)&Bs[row * 72 + skc] = pb;
      }
      __syncthreads();
#pragma unroll
      for (int kk = 0; kk < 2; ++kk) {
        bf16x8 af[4], bfr[4];
#pragma unroll
        for (int m = 0; m < 4; ++m)
          af[m] = *(const bf16x8*)&As[(wr * 64 + m * 16 + lr) * 72 + kk * 32 + lg * 8];
#pragma unroll
        for (int n = 0; n < 4; ++n)
          bfr[n] = *(const bf16x8*)&Bs[(wc * 64 + n * 16 + lr) * 72 + kk * 32 + lg * 8];
#pragma unroll
        for (int m = 0; m < 4; ++m)
#pragma unroll
          for (int n = 0; n < 4; ++n)
            acc[m][n] = __builtin_amdgcn_mfma_f32_16x16x32_bf16(af[m], bfr[n],
                                                                acc[m][n], 0, 0, 0);
      }
    }
  }

  // epilogue: D col = lane&15, row = (lane>>4)*4 + j   [m89-verified]
  const long crow0 = (long)bm * 128 + wr * 64;
  const int col0 = bn * 128 + wc * 64;
#pragma unroll
  for (int n = 0; n < 4; ++n) {
    const int col = col0 + n * 16 + lr;
    const float bv = bias ? bias[col] : 0.f;
#pragma unroll
    for (int m = 0; m < 4; ++m) {
      const long rbase = (crow0 + m * 16 + lg * 4) * ldc + col;
#pragma unroll
      for (int j = 0; j < 4; ++j) C[rbase + (long)j * ldc] = acc[m][n][j] + bv;
    }
  }
}

// ---------------- fused gelu(A*x+B*y+C) -> end_conv einsum ------------------
__global__ __launch_bounds__(256) void k_oe(const float* __restrict__ x,
                                            const float* __restrict__ yg,
                                            const float* __restrict__ cf,
                                            const float* __restrict__ ec_w,
                                            const float* __restrict__ ec_b,
                                            float* __restrict__ oe) {
  const int b = blockIdx.x;
  const int v = blockIdx.y * 256 + threadIdx.x;
  __shared__ float ecs[512];
  __shared__ float cfs[96];
  __shared__ float ebs[4];
  if (threadIdx.x < 96) cfs[threadIdx.x] = cf[threadIdx.x];
  if (threadIdx.x < 4) ebs[threadIdx.x] = ec_b[threadIdx.x];
  for (int i = threadIdx.x; i < 512; i += 256) ecs[i] = ec_w[i];
  __syncthreads();
  float xl[4], yl[4];
#pragma unroll
  for (int l = 0; l < 4; ++l) {
    long off = ((long)b * 4 + l) * 512 + v;
    xl[l] = x[off];
    yl[l] = yg[off];
  }
  float o0 = ebs[0], o1 = ebs[1], o2 = ebs[2], o3 = ebs[3];
  for (int cc = 0; cc < 32; ++cc) {
    float A = cfs[cc], Bv = cfs[32 + cc], Cv = cfs[64 + cc];
#pragma unroll
    for (int l = 0; l < 4; ++l) {
      float u = fmaf(A, xl[l], fmaf(Bv, yl[l], Cv));
      float gu = 0.5f * u * (1.f + erff(u * 0.70710678118654752f));
      o0 = fmaf(ecs[(0 * 32 + cc) * 4 + l], gu, o0);
      o1 = fmaf(ecs[(1 * 32 + cc) * 4 + l], gu, o1);
      o2 = fmaf(ecs[(2 * 32 + cc) * 4 + l], gu, o2);
      o3 = fmaf(ecs[(3 * 32 + cc) * 4 + l], gu, o3);
    }
  }
  oe[((long)b * 4 + 0) * 512 + v] = o0;
  oe[((long)b * 4 + 1) * 512 + v] = o1;
  oe[((long)b * 4 + 2) * 512 + v] = o2;
  oe[((long)b * 4 + 3) * 512 + v] = o3;
}

// ---------------- LN(x+g) then softmax -> xg, gw (width 512) ----------------
__global__ __launch_bounds__(256) void k_lngw(const float* __restrict__ x,
                                              const float* __restrict__ g,
                                              const float* __restrict__ gg,
                                              const float* __restrict__ gb,
                                              float* __restrict__ xg,
                                              float* __restrict__ gw) {
  const long r = blockIdx.x;
  const int tid = threadIdx.x;
  __shared__ float red[4];
  const float* xp = x + r * 512;
  const float* gp = g + r * 512;
  float a0 = xp[tid] + gp[tid];
  float a1 = xp[tid + 256] + gp[tid + 256];
  float m = bsum(a0 + a1, red) * (1.f / 512.f);
  float q = (a0 - m) * (a0 - m) + (a1 - m) * (a1 - m);
  float var = bsum(q, red) * (1.f / 512.f);
  float rstd = rsqrtf(var + 1e-5f);
  float v0 = (a0 - m) * rstd * gg[tid] + gb[tid];
  float v1 = (a1 - m) * rstd * gg[tid + 256] + gb[tid + 256];
  xg[r * 512 + tid] = v0;
  xg[r * 512 + tid + 256] = v1;
  float mx = bmax(fmaxf(v0, v1), red);
  float e0 = expf(v0 - mx), e1 = expf(v1 - mx);
  float s = bsum(e0 + e1, red);
  float inv = 1.f / s;
  gw[r * 512 + tid] = e0 * inv;
  gw[r * 512 + tid + 256] = e1 * inv;
}

// ---------------- LSTM gate pointwise -------------------------------------
__global__ __launch_bounds__(256) void k_gates(
    const float* __restrict__ z, const float* __restrict__ Wb,
    const float* __restrict__ Ub, const float* __restrict__ gw0,
    const float* __restrict__ gw1, float* __restrict__ h, float* __restrict__ c,
    float* __restrict__ yl, int l, int t) {
  const int dir = blockIdx.y;
  const int idx = blockIdx.x * 256 + threadIdx.x;
  const int b = idx >> 9, o = idx & 511;
  const float* zp = z + (long)dir * (1024L * 2560) + (long)b * 2560 + o;
  const long boff = ((long)(dir * 4 + l) * 5) * 512 + o;
  float zi = zp[0] + Wb[boff] + Ub[boff];
  float zf = zp[512] + Wb[boff + 512] + Ub[boff + 512];
  float zo = zp[1024] + Wb[boff + 1024] + Ub[boff + 1024];
  float zc = zp[1536] + Wb[boff + 1536] + Ub[boff + 1536];
  float zs = zp[2048] + Wb[boff + 2048] + Ub[boff + 2048];
  const float* gwp = dir ? gw1 : gw0;
  float dw = gwp[(long)b * 2048 + o];
  const long hc = ((long)(dir * 4 + l) * 1024 + b) * 512 + o;
  float i_t = sigmoidf(zi), f_t = sigmoidf(zf), o_t = sigmoidf(zo);
  float ch = tanhf(zc);
  float s_t = sigmoidf(zs) * dw;
  float cn = f_t * c[hc] + i_t * ch * s_t;
  float hn = o_t * tanhf(cn);
  c[hc] = cn;
  h[hc] = hn;
  if (l == 3) {
    int tok = dir ? (3 - t) : t;
    yl[(long)b * 4096 + (long)tok * 1024 + dir * 512 + o] = hn;
  }
}

// ---------------- tiny attention (N=4 tokens), block = (b, head) ------------
__global__ __launch_bounds__(256) void k_attn(const float* __restrict__ qkv,
                                              float* __restrict__ out, int d,
                                              float scale) {
  const int b = blockIdx.x, h = blockIdx.y;
  __shared__ float qs[4][256], ks[4][256], vs[4][256];
  __shared__ float sc[4][4];
  const int tid = threadIdx.x;
  for (int tok = 0; tok < 4; ++tok) {
    const float* base = qkv + ((long)b * 4 + tok) * 3072 + h * d;
    for (int j = tid; j < d; j += 256) {
      qs[tok][j] = base[j];
      ks[tok][j] = base[1024 + j];
      vs[tok][j] = base[2048 + j];
    }
  }
  __syncthreads();
  if (tid < 16) {
    int i = tid >> 2, j = tid & 3;
    float s = 0.f;
    for (int dd = 0; dd < d; ++dd) s += qs[i][dd] * ks[j][dd];
    sc[i][j] = s * scale;
  }
  __syncthreads();
  if (tid < 4) {
    float m = fmaxf(fmaxf(sc[tid][0], sc[tid][1]), fmaxf(sc[tid][2], sc[tid][3]));
    float e0 = expf(sc[tid][0] - m), e1 = expf(sc[tid][1] - m);
    float e2 = expf(sc[tid][2] - m), e3 = expf(sc[tid][3] - m);
    float inv = 1.f / (e0 + e1 + e2 + e3);
    sc[tid][0] = e0 * inv;
    sc[tid][1] = e1 * inv;
    sc[tid][2] = e2 * inv;
    sc[tid][3] = e3 * inv;
  }
  __syncthreads();
  for (int idx = tid; idx < 4 * d; idx += 256) {
    int i = idx / d, dd = idx - i * d;
    float o = sc[i][0] * vs[0][dd] + sc[i][1] * vs[1][dd] + sc[i][2] * vs[2][dd] +
              sc[i][3] * vs[3][dd];
    out[((long)b * 4 + i) * 1024 + (long)h * d + dd] = o;
  }
}

// ---------------- LayerNorm width 1024 -------------------------------------
__global__ __launch_bounds__(256) void k_ln1024(const float* __restrict__ in,
                                                const float* __restrict__ gg,
                                                const float* __restrict__ bb,
                                                float* __restrict__ out) {
  const long r = blockIdx.x;
  const int tid = threadIdx.x;
  __shared__ float red[4];
  const float* ip = in + r * 1024;
  float v[4];
#pragma unroll
  for (int i = 0; i < 4; ++i) v[i] = ip[tid + i * 256];
  float m = bsum(v[0] + v[1] + v[2] + v[3], red) * (1.f / 1024.f);
  float q = 0.f;
#pragma unroll
  for (int i = 0; i < 4; ++i) q += (v[i] - m) * (v[i] - m);
  float rstd = rsqrtf(bsum(q, red) * (1.f / 1024.f) + 1e-5f);
  float* op = out + r * 1024;
#pragma unroll
  for (int i = 0; i < 4; ++i) {
    int cidx = tid + i * 256;
    op[cidx] = (v[i] - m) * rstd * gg[cidx] + bb[cidx];
  }
}

// ---------------- DMIN LN + sigmoid gate -----------------------------------
__global__ __launch_bounds__(256) void k_dmin(const float* __restrict__ zin,
                                              const float* __restrict__ ori,
                                              const float* __restrict__ gg,
                                              const float* __restrict__ bb,
                                              float* __restrict__ y2) {
  const long r = blockIdx.x;
  const int tid = threadIdx.x;
  __shared__ float red[4];
  const float* ip = zin + r * 1024;
  float v[4];
#pragma unroll
  for (int i = 0; i < 4; ++i) v[i] = ip[tid + i * 256];
  float m = bsum(v[0] + v[1] + v[2] + v[3], red) * (1.f / 1024.f);
  float q = 0.f;
#pragma unroll
  for (int i = 0; i < 4; ++i) q += (v[i] - m) * (v[i] - m);
  float rstd = rsqrtf(bsum(q, red) * (1.f / 1024.f) + 1e-5f);
#pragma unroll
  for (int i = 0; i < 4; ++i) {
    int cidx = tid + i * 256;
    float ln = (v[i] - m) * rstd * gg[cidx] + bb[cidx];
    y2[r * 1024 + cidx] = ori[r * 1024 + cidx] * sigmoidf(ln);
  }
}

// ---------------- pwconv over feature axis (C=4 bag -> 1, k=3, pad 1) -------
__global__ __launch_bounds__(256) void k_pw(const float* __restrict__ y2,
                                            const float* __restrict__ pw,
                                            const float* __restrict__ pb,
                                            float* __restrict__ xfer) {
  const int b = blockIdx.x;
  __shared__ float w[12];
  if (threadIdx.x < 12) w[threadIdx.x] = pw[threadIdx.x];
  __syncthreads();
  const float bias = pb[0];
  for (int e = threadIdx.x; e < 1024; e += 256) {
    float acc = bias;
#pragma unroll
    for (int c = 0; c < 4; ++c) {
      const float* yr = y2 + (long)b * 4096 + (long)c * 1024;
      if (e > 0) acc = fmaf(yr[e - 1], w[c * 3 + 0], acc);
      acc = fmaf(yr[e], w[c * 3 + 1], acc);
      if (e < 1023) acc = fmaf(yr[e + 1], w[c * 3 + 2], acc);
    }
    xfer[(long)b * 1024 + e] = acc;
  }
}

// ---------------- final fc: [1024] -> [7] ----------------------------------
__global__ __launch_bounds__(256) void k_fc(const float* __restrict__ xf,
                                            const float* __restrict__ fw,
                                            const float* __restrict__ fb,
                                            float* __restrict__ out) {
  const int b = blockIdx.x, tid = threadIdx.x;
  float acc[7] = {0.f, 0.f, 0.f, 0.f, 0.f, 0.f, 0.f};
  for (int e = tid; e < 1024; e += 256) {
    float xv = xf[(long)b * 1024 + e];
#pragma unroll
    for (int j = 0; j < 7; ++j) acc[j] = fmaf(xv, fw[j * 1024 + e], acc[j]);
  }
  __shared__ float red[4][7];
#pragma unroll
  for (int j = 0; j < 7; ++j) {
    float v = acc[j];
#pragma unroll
    for (int off = 32; off; off >>= 1) v += __shfl_down(v, off, 64);
    if ((tid & 63) == 0) red[tid >> 6][j] = v;
  }
  __syncthreads();
  if (tid < 7)
    out[(long)b * 7 + tid] =
        red[0][tid] + red[1][tid] + red[2][tid] + red[3][tid] + fb[tid];
}

// ===========================================================================
extern "C" void kernel_launch(void* const* d_in, const int* in_sizes, int n_in,
                              void* d_out, int out_size, void* d_ws,
                              size_t ws_size, hipStream_t stream) {
  const float* x = (const float*)d_in[0];
  const float* nv1 = (const float*)d_in[1];
  const float* nv2 = (const float*)d_in[2];
  const float* sc_w = (const float*)d_in[3];
  const float* sc_b = (const float*)d_in[4];
  const float* mp_w = (const float*)d_in[5];
  const float* mp_b = (const float*)d_in[6];
  const float* ec_w = (const float*)d_in[7];
  const float* ec_b = (const float*)d_in[8];
  const float* gbl_w = (const float*)d_in[9];
  const float* gbl_b = (const float*)d_in[10];
  const float* gbln_g = (const float*)d_in[11];
  const float* gbln_b = (const float*)d_in[12];
  const float* lstm_W = (const float*)d_in[13];
  const float* lstm_Wb = (const float*)d_in[14];
  const float* lstm_U = (const float*)d_in[15];
  const float* lstm_Ub = (const float*)d_in[16];
  const float* mha_in_w = (const float*)d_in[17];
  const float* mha_in_b = (const float*)d_in[18];
  const float* mha_out_w = (const float*)d_in[19];
  const float* mha_out_b = (const float*)d_in[20];
  const float* ln1_g = (const float*)d_in[21];
  const float* ln1_b = (const float*)d_in[22];
  const float* qkv_w = (const float*)d_in[23];
  const float* dmin_g = (const float*)d_in[24];
  const float* dmin_b = (const float*)d_in[25];
  const float* pw_w = (const float*)d_in[26];
  const float* pw_b = (const float*)d_in[27];
  const float* fc_w = (const float*)d_in[28];
  const float* fc_b = (const float*)d_in[29];

  float* ws = (float*)d_ws;
  float* out = (float*)d_out;
  float* xfer = out + 1024 * 7;

  // workspace layout (floats). post-LSTM buffers alias the graph/LSTM region.
  float* wA = ws + 0;           //   262,144  adjacency a [512][512]
  float* wY = ws + 262144;      // 2,097,152  y_graph, then g
  float* wOE = ws + 2359296;    // 2,097,152  oe
  float* wXG = ws + 4456448;    // 2,097,152  xg
  float* wGW = ws + 6553600;    // 2,097,152  gw
  float* wH = ws + 8650752;     // 4,194,304  h state [2][4][1024][512]
  float* wC = ws + 12845056;    // 4,194,304  c state
  float* wZ = ws + 17039360;    // 5,242,880  z [2][1024][2560]   (ends 22,282,240)
  float* wQKV = ws + 0;         // 12,582,912 (aliases dead graph bufs post-LSTM)
  float* wATT = ws + 12582912;  // 4,194,304
  float* wTMP = ws + 16777216;  // 4,194,304  mha_y, then y2
  float* wYL = ws + 22282240;   // 4,194,304  lstm output y [1024][4][1024]
  float* wORI = ws + 26476544;  // 4,194,304  ori (after ln1)
  float* wCF = ws + 30670848;   //        96  folded mixprop coefs

  // zero LSTM h/c state (contiguous)
  hipMemsetAsync(wH, 0, (size_t)8388608 * sizeof(float), stream);

  // ---- graph block ----
  k_adj<<<512, 256, 0, stream>>>(nv1, nv2, wA);
  k_coef<<<1, 64, 0, stream>>>(mp_w, mp_b, sc_w, sc_b, wCF);
  // y = X @ a^T   (M=4096, N=512, K=512)
  k_mgemm<<<dim3(32, 4, 1), 256, 0, stream>>>(x, 512, 0, wA, 512, 0, x, 512, 0,
                                              wA, 512, 0, nullptr, wY, 512, 0,
                                              512, 0);
  k_oe<<<dim3(1024, 2, 1), 256, 0, stream>>>(x, wY, wCF, ec_w, ec_b, wOE);
  // g = oe @ gbl_w^T + gbl_b  (M=4096, N=512, K=512) -> reuse wY
  k_mgemm<<<dim3(32, 4, 1), 256, 0, stream>>>(wOE, 512, 0, gbl_w, 512, 0, wOE,
                                              512, 0, gbl_w, 512, 0, gbl_b, wY,
                                              512, 0, 512, 0);
  k_lngw<<<4096, 256, 0, stream>>>(x, wY, gbln_g, gbln_b, wXG, wGW);

  // ---- bidirectional 4-layer LSTM (dirs batched on grid.z) ----
  for (int t = 0; t < 4; ++t) {
    for (int l = 0; l < 4; ++l) {
      const float* A0;
      long lda, sAz;
      if (l == 0) {
        A0 = wXG + (long)t * 512;
        lda = 2048;
        sAz = (long)(3 - 2 * t) * 512;  // dir1 starts at token 3-t
      } else {
        A0 = wH + (long)(l - 1) * 524288;
        lda = 512;
        sAz = 4L * 524288;
      }
      const float* A2 = wH + (long)l * 524288;
      const float* Bw = lstm_W + (long)l * 1310720;
      const float* Bu = lstm_U + (long)l * 1310720;
      // z = x_t @ W^T + h @ U^T   (M=1024, N=2560, K=512 dual)
      k_mgemm<<<dim3(8, 20, 2), 256, 0, stream>>>(
          A0, lda, sAz, Bw, 512, 5242880L, A2, 512, 4L * 524288, Bu, 512,
          5242880L, nullptr, wZ, 2560, 2621440L, 512, 1);
      k_gates<<<dim3(2048, 2, 1), 256, 0, stream>>>(
          wZ, lstm_Wb, lstm_Ub, wGW + (long)t * 512, wGW + (long)(3 - t) * 512,
          wH, wC, wYL, l, t);
    }
  }

  // ---- MHA (4 heads, d=256) ----
  k_mgemm<<<dim3(32, 24, 1), 256, 0, stream>>>(
      wYL, 1024, 0, mha_in_w, 1024, 0, wYL, 1024, 0, mha_in_w, 1024, 0,
      mha_in_b, wQKV, 3072, 0, 1024, 0);
  k_attn<<<dim3(1024, 4, 1), 256, 0, stream>>>(wQKV, wATT, 256, 1.f / 16.f);
  k_mgemm<<<dim3(32, 8, 1), 256, 0, stream>>>(
      wATT, 1024, 0, mha_out_w, 1024, 0, wATT, 1024, 0, mha_out_w, 1024, 0,
      mha_out_b, wTMP, 1024, 0, 1024, 0);
  k_ln1024<<<4096, 256, 0, stream>>>(wTMP, ln1_g, ln1_b, wORI);

  // ---- MIL self-attention fusion (8 heads, d=128) ----
  k_mgemm<<<dim3(32, 24, 1), 256, 0, stream>>>(
      wORI, 1024, 0, qkv_w, 1024, 0, wORI, 1024, 0, qkv_w, 1024, 0, nullptr,
      wQKV, 3072, 0, 1024, 0);
  k_attn<<<dim3(1024, 8, 1), 256, 0, stream>>>(wQKV, wATT, 128,
                                               0.08838834764831845f);
  k_dmin<<<4096, 256, 0, stream>>>(wATT, wORI, dmin_g, dmin_b, wTMP);

  // ---- pwconv + fc ----
  k_pw<<<1024, 256, 0, stream>>>(wTMP, pw_w, pw_b, xfer);
  k_fc<<<1024, 256, 0, stream>>>(xfer, fc_w, fc_b, out);
}

// Round 5
// 933.235 us; speedup vs baseline: 4.2890x; 1.8563x over previous
//
#include <hip/hip_runtime.h>

#define DEV __device__ __forceinline__

typedef __attribute__((ext_vector_type(8))) short bf16x8;
typedef __attribute__((ext_vector_type(8))) unsigned short u16x8;
typedef __attribute__((ext_vector_type(4))) float f32x4;

DEV unsigned short f2b(float f) {
  union { float f; unsigned u; } v;
  v.f = f;
  unsigned r = v.u + 0x7FFFu + ((v.u >> 16) & 1u);
  return (unsigned short)(r >> 16);
}
DEV float b2f(unsigned short u) {
  union { unsigned u; float f; } v;
  v.u = ((unsigned)u) << 16;
  return v.f;
}
DEV float sigmoidf(float x) { return 1.f / (1.f + expf(-x)); }

// async global->LDS, 16B per lane; LDS dest = wave-uniform base + lane*16
#define GL16(gp, lp)                                                        \
  __builtin_amdgcn_global_load_lds(                                         \
      (const __attribute__((address_space(1))) unsigned int*)(gp),          \
      (__attribute__((address_space(3))) unsigned int*)(lp), 16, 0, 0)

// ---------------- block reduce helpers (blockDim == 256) ----------------
DEV float bsum(float v, float* red) {
#pragma unroll
  for (int off = 32; off; off >>= 1) v += __shfl_down(v, off, 64);
  int tid = threadIdx.x;
  __syncthreads();
  if ((tid & 63) == 0) red[tid >> 6] = v;
  __syncthreads();
  return red[0] + red[1] + red[2] + red[3];
}
DEV float bmax(float v, float* red) {
#pragma unroll
  for (int off = 32; off; off >>= 1) v = fmaxf(v, __shfl_down(v, off, 64));
  int tid = threadIdx.x;
  __syncthreads();
  if ((tid & 63) == 0) red[tid >> 6] = v;
  __syncthreads();
  return fmaxf(fmaxf(red[0], red[1]), fmaxf(red[2], red[3]));
}

// ---------------- f32 -> bf16 bulk convert (n = grid*2048 elems) -----------
__global__ __launch_bounds__(256) void k_cvt(const float* __restrict__ in,
                                             unsigned short* __restrict__ out) {
  long i = ((long)blockIdx.x * 256 + threadIdx.x) * 8;
  float4 a = *(const float4*)(in + i);
  float4 b = *(const float4*)(in + i + 4);
  u16x8 o;
  o[0] = f2b(a.x); o[1] = f2b(a.y); o[2] = f2b(a.z); o[3] = f2b(a.w);
  o[4] = f2b(b.x); o[5] = f2b(b.y); o[6] = f2b(b.z); o[7] = f2b(b.w);
  *(u16x8*)(out + i) = o;
}

// ---------------- adjacency: a = (softmax(relu(nv1@nv2)) + I)/2, bf16 ------
__global__ __launch_bounds__(256) void k_adj(const float* __restrict__ nv1,
                                             const float* __restrict__ nv2,
                                             unsigned short* __restrict__ a) {
  const int v = blockIdx.x, tid = threadIdx.x;
  __shared__ float n1[32];
  __shared__ float red[4];
  if (tid < 32) n1[tid] = nv1[v * 32 + tid];
  __syncthreads();
  float r0, r1;
  {
    float s = 0.f;
#pragma unroll 8
    for (int k = 0; k < 32; ++k) s += n1[k] * nv2[k * 512 + tid];
    r0 = fmaxf(s, 0.f);
  }
  {
    float s = 0.f;
#pragma unroll 8
    for (int k = 0; k < 32; ++k) s += n1[k] * nv2[k * 512 + tid + 256];
    r1 = fmaxf(s, 0.f);
  }
  float mx = bmax(fmaxf(r0, r1), red);
  float e0 = expf(r0 - mx), e1 = expf(r1 - mx);
  float s = bsum(e0 + e1, red);
  float inv = 1.f / s;
  int w0 = tid, w1 = tid + 256;
  a[(long)v * 512 + w0] = f2b((e0 * inv + (w0 == v ? 1.f : 0.f)) * 0.5f);
  a[(long)v * 512 + w1] = f2b((e1 * inv + (w1 == v ? 1.f : 0.f)) * 0.5f);
}

// ---------------- fold start_conv + mixprop + 1x1 mlp into coef vectors ----
__global__ void k_coef(const float* __restrict__ mp_w, const float* __restrict__ mp_b,
                       const float* __restrict__ sc_w, const float* __restrict__ sc_b,
                       float* __restrict__ cf) {
  int o = threadIdx.x;
  if (o < 32) {
    float A = 0.f, Bv = 0.f, Cv = 0.f;
    for (int cc = 0; cc < 32; ++cc) {
      float m1 = mp_w[o * 64 + cc], m2 = mp_w[o * 64 + 32 + cc];
      float sw = sc_w[cc], sb = sc_b[cc];
      A += (m1 + 0.7f * m2) * sw;
      Bv += 0.3f * m2 * sw;
      Cv += (m1 + m2) * sb;
    }
    cf[o] = A;
    cf[32 + o] = Bv;
    cf[64 + o] = Cv + mp_b[o];
  }
}

// ---------------- shared MFMA GEMM core: acc += A[128 rows] @ B[128 rows]^T -
// bf16 operands in global, staged via global_load_lds into linear LDS tiles.
DEV void gemm_tile(const unsigned short* Ap, long lda, const unsigned short* Bp,
                   long ldb, int K, unsigned short* As, unsigned short* Bs,
                   int bm, int bn, int tid, f32x4 (&acc)[4][4]) {
  const int lane = tid & 63, wave = tid >> 6;
  const int wr = wave >> 1, wc = wave & 1;
  const int lr = lane & 15, lg = lane >> 4;
  const int sg = tid >> 3, sc8 = (tid & 7) * 8;
  const unsigned short* Arow = Ap + (long)(bm * 128 + sg) * lda + sc8;
  const unsigned short* Brow = Bp + (long)(bn * 128 + sg) * ldb + sc8;
  for (int k0 = 0; k0 < K; k0 += 64) {
    __syncthreads();
#pragma unroll
    for (int i = 0; i < 4; ++i) {
      GL16(Arow + (long)(i * 32) * lda + k0, &As[i * 2048 + wave * 512]);
      GL16(Brow + (long)(i * 32) * ldb + k0, &Bs[i * 2048 + wave * 512]);
    }
    __syncthreads();
#pragma unroll
    for (int kk = 0; kk < 2; ++kk) {
      bf16x8 af[4], bq[4];
#pragma unroll
      for (int m = 0; m < 4; ++m)
        af[m] = *(const bf16x8*)&As[(wr * 64 + m * 16 + lr) * 64 + kk * 32 + lg * 8];
#pragma unroll
      for (int n = 0; n < 4; ++n)
        bq[n] = *(const bf16x8*)&Bs[(wc * 64 + n * 16 + lr) * 64 + kk * 32 + lg * 8];
#pragma unroll
      for (int m = 0; m < 4; ++m)
#pragma unroll
        for (int n = 0; n < 4; ++n)
          acc[m][n] = __builtin_amdgcn_mfma_f32_16x16x32_bf16(af[m], bq[n],
                                                              acc[m][n], 0, 0, 0);
    }
  }
}

// ---------------- generic bf16 NT GEMM, f32 out (+bias) --------------------
__global__ __launch_bounds__(256) void k_bgemm(
    const unsigned short* __restrict__ A, long lda,
    const unsigned short* __restrict__ B, long ldb,
    const float* __restrict__ bias, float* __restrict__ C, long ldc, int K) {
  __shared__ unsigned short As[8192], Bs[8192];
  f32x4 acc[4][4];
#pragma unroll
  for (int m = 0; m < 4; ++m)
#pragma unroll
    for (int n = 0; n < 4; ++n) acc[m][n] = (f32x4){0.f, 0.f, 0.f, 0.f};
  gemm_tile(A, lda, B, ldb, K, As, Bs, blockIdx.x, blockIdx.y, threadIdx.x, acc);
  const int lane = threadIdx.x & 63, wave = threadIdx.x >> 6;
  const int wr = wave >> 1, wc = wave & 1, lr = lane & 15, lg = lane >> 4;
  const long crow0 = (long)blockIdx.x * 128 + wr * 64;
  const int col0 = blockIdx.y * 128 + wc * 64;
#pragma unroll
  for (int n = 0; n < 4; ++n) {
    const int col = col0 + n * 16 + lr;
    const float bv = bias ? bias[col] : 0.f;
#pragma unroll
    for (int m = 0; m < 4; ++m) {
      const long rbase = (crow0 + m * 16 + lg * 4) * ldc + col;
#pragma unroll
      for (int j = 0; j < 4; ++j) C[rbase + (long)j * ldc] = acc[m][n][j] + bv;
    }
  }
}

// ---------------- LSTM stage GEMM: z = a0@W^T + a2@U^T, bf16 out -----------
struct LStage {
  const unsigned short* a0[6];
  const unsigned short* a2[6];
  const unsigned short* w[6];
  const unsigned short* u[6];
  unsigned short* zo[6];
  long lda0[6];
};

__global__ __launch_bounds__(256) void k_lgemm(LStage p) {
  __shared__ unsigned short As[8192], Bs[8192];
  const int z = blockIdx.z;
  f32x4 acc[4][4];
#pragma unroll
  for (int m = 0; m < 4; ++m)
#pragma unroll
    for (int n = 0; n < 4; ++n) acc[m][n] = (f32x4){0.f, 0.f, 0.f, 0.f};
  gemm_tile(p.a0[z], p.lda0[z], p.w[z], 512, 512, As, Bs, blockIdx.x,
            blockIdx.y, threadIdx.x, acc);
  gemm_tile(p.a2[z], 512, p.u[z], 512, 512, As, Bs, blockIdx.x, blockIdx.y,
            threadIdx.x, acc);
  unsigned short* zo = p.zo[z];
  const int lane = threadIdx.x & 63, wave = threadIdx.x >> 6;
  const int wr = wave >> 1, wc = wave & 1, lr = lane & 15, lg = lane >> 4;
  const long crow0 = (long)blockIdx.x * 128 + wr * 64;
  const int col0 = blockIdx.y * 128 + wc * 64;
#pragma unroll
  for (int n = 0; n < 4; ++n) {
    const int col = col0 + n * 16 + lr;
#pragma unroll
    for (int m = 0; m < 4; ++m) {
      const long rbase = (crow0 + m * 16 + lg * 4) * 2560 + col;
#pragma unroll
      for (int j = 0; j < 4; ++j) zo[rbase + (long)j * 2560] = f2b(acc[m][n][j]);
    }
  }
}

// ---------------- LSTM gates (per wavefront stage) -------------------------
struct GStage {
  const unsigned short* z[6];
  int tt[6];
  int ll[6];
};

__global__ __launch_bounds__(256) void k_gates(
    GStage g, const float* __restrict__ Wb, const float* __restrict__ Ub,
    const unsigned short* __restrict__ gwbf, unsigned short* __restrict__ hbf,
    float* __restrict__ c, unsigned short* __restrict__ ylbf) {
  const int s = blockIdx.y, dir = s & 1;
  const int t = g.tt[s], l = g.ll[s];
  const unsigned short* zp = g.z[s];
  const int idx = blockIdx.x * 256 + threadIdx.x;
  const int b = idx >> 9, o = idx & 511;
  const long boff = (long)(dir * 4 + l) * 2560 + o;
  const long zb = (long)b * 2560 + o;
  float zi = b2f(zp[zb]) + Wb[boff] + Ub[boff];
  float zf = b2f(zp[zb + 512]) + Wb[boff + 512] + Ub[boff + 512];
  float zoo = b2f(zp[zb + 1024]) + Wb[boff + 1024] + Ub[boff + 1024];
  float zc = b2f(zp[zb + 1536]) + Wb[boff + 1536] + Ub[boff + 1536];
  float zs = b2f(zp[zb + 2048]) + Wb[boff + 2048] + Ub[boff + 2048];
  const int tok = dir ? 3 - t : t;
  float dw = b2f(gwbf[(long)b * 2048 + tok * 512 + o]);
  const long hc = ((long)(dir * 4 + l) * 1024 + b) * 512 + o;
  float i_t = sigmoidf(zi), f_t = sigmoidf(zf), o_t = sigmoidf(zoo);
  float ch = tanhf(zc);
  float s_t = sigmoidf(zs) * dw;
  float cn = f_t * c[hc] + i_t * ch * s_t;
  float hn = o_t * tanhf(cn);
  c[hc] = cn;
  hbf[hc] = f2b(hn);
  if (l == 3) ylbf[(long)b * 4096 + tok * 1024 + dir * 512 + o] = f2b(hn);
}

// ---------------- fused gelu(A*x+B*y+C) -> end_conv einsum, bf16 out -------
__global__ __launch_bounds__(256) void k_oe(const float* __restrict__ x,
                                            const float* __restrict__ yg,
                                            const float* __restrict__ cf,
                                            const float* __restrict__ ec_w,
                                            const float* __restrict__ ec_b,
                                            unsigned short* __restrict__ oe) {
  const int b = blockIdx.x;
  const int v = blockIdx.y * 256 + threadIdx.x;
  __shared__ float ecs[512];
  __shared__ float cfs[96];
  __shared__ float ebs[4];
  if (threadIdx.x < 96) cfs[threadIdx.x] = cf[threadIdx.x];
  if (threadIdx.x < 4) ebs[threadIdx.x] = ec_b[threadIdx.x];
  for (int i = threadIdx.x; i < 512; i += 256) ecs[i] = ec_w[i];
  __syncthreads();
  float xl[4], yl[4];
#pragma unroll
  for (int l = 0; l < 4; ++l) {
    long off = ((long)b * 4 + l) * 512 + v;
    xl[l] = x[off];
    yl[l] = yg[off];
  }
  float o0 = ebs[0], o1 = ebs[1], o2 = ebs[2], o3 = ebs[3];
  for (int cc = 0; cc < 32; ++cc) {
    float A = cfs[cc], Bv = cfs[32 + cc], Cv = cfs[64 + cc];
#pragma unroll
    for (int l = 0; l < 4; ++l) {
      float u = fmaf(A, xl[l], fmaf(Bv, yl[l], Cv));
      float gu = 0.5f * u * (1.f + erff(u * 0.70710678118654752f));
      o0 = fmaf(ecs[(0 * 32 + cc) * 4 + l], gu, o0);
      o1 = fmaf(ecs[(1 * 32 + cc) * 4 + l], gu, o1);
      o2 = fmaf(ecs[(2 * 32 + cc) * 4 + l], gu, o2);
      o3 = fmaf(ecs[(3 * 32 + cc) * 4 + l], gu, o3);
    }
  }
  oe[((long)b * 4 + 0) * 512 + v] = f2b(o0);
  oe[((long)b * 4 + 1) * 512 + v] = f2b(o1);
  oe[((long)b * 4 + 2) * 512 + v] = f2b(o2);
  oe[((long)b * 4 + 3) * 512 + v] = f2b(o3);
}

// ---------------- LN(x+g) then softmax -> xg_bf, gw_bf ---------------------
__global__ __launch_bounds__(256) void k_lngw(const float* __restrict__ x,
                                              const float* __restrict__ g,
                                              const float* __restrict__ gg,
                                              const float* __restrict__ gb,
                                              unsigned short* __restrict__ xg,
                                              unsigned short* __restrict__ gw) {
  const long r = blockIdx.x;
  const int tid = threadIdx.x;
  __shared__ float red[4];
  const float* xp = x + r * 512;
  const float* gp = g + r * 512;
  float a0 = xp[tid] + gp[tid];
  float a1 = xp[tid + 256] + gp[tid + 256];
  float m = bsum(a0 + a1, red) * (1.f / 512.f);
  float q = (a0 - m) * (a0 - m) + (a1 - m) * (a1 - m);
  float var = bsum(q, red) * (1.f / 512.f);
  float rstd = rsqrtf(var + 1e-5f);
  float v0 = (a0 - m) * rstd * gg[tid] + gb[tid];
  float v1 = (a1 - m) * rstd * gg[tid + 256] + gb[tid + 256];
  xg[r * 512 + tid] = f2b(v0);
  xg[r * 512 + tid + 256] = f2b(v1);
  float mx = bmax(fmaxf(v0, v1), red);
  float e0 = expf(v0 - mx), e1 = expf(v1 - mx);
  float s = bsum(e0 + e1, red);
  float inv = 1.f / s;
  gw[r * 512 + tid] = f2b(e0 * inv);
  gw[r * 512 + tid + 256] = f2b(e1 * inv);
}

// ---------------- tiny attention (N=4 tokens), block = (b, head) ------------
__global__ __launch_bounds__(256) void k_attn(const float* __restrict__ qkv,
                                              unsigned short* __restrict__ outb,
                                              float* __restrict__ outf, int d,
                                              float scale, int obf) {
  const int b = blockIdx.x, h = blockIdx.y;
  __shared__ float qs[4][256], ks[4][256], vs[4][256];
  __shared__ float sc[4][4];
  const int tid = threadIdx.x;
  for (int tok = 0; tok < 4; ++tok) {
    const float* base = qkv + ((long)b * 4 + tok) * 3072 + h * d;
    for (int j = tid; j < d; j += 256) {
      qs[tok][j] = base[j];
      ks[tok][j] = base[1024 + j];
      vs[tok][j] = base[2048 + j];
    }
  }
  __syncthreads();
  if (tid < 16) {
    int i = tid >> 2, j = tid & 3;
    float s = 0.f;
    for (int dd = 0; dd < d; ++dd) s += qs[i][dd] * ks[j][dd];
    sc[i][j] = s * scale;
  }
  __syncthreads();
  if (tid < 4) {
    float m = fmaxf(fmaxf(sc[tid][0], sc[tid][1]), fmaxf(sc[tid][2], sc[tid][3]));
    float e0 = expf(sc[tid][0] - m), e1 = expf(sc[tid][1] - m);
    float e2 = expf(sc[tid][2] - m), e3 = expf(sc[tid][3] - m);
    float inv = 1.f / (e0 + e1 + e2 + e3);
    sc[tid][0] = e0 * inv;
    sc[tid][1] = e1 * inv;
    sc[tid][2] = e2 * inv;
    sc[tid][3] = e3 * inv;
  }
  __syncthreads();
  for (int idx = tid; idx < 4 * d; idx += 256) {
    int i = idx / d, dd = idx - i * d;
    float o = sc[i][0] * vs[0][dd] + sc[i][1] * vs[1][dd] + sc[i][2] * vs[2][dd] +
              sc[i][3] * vs[3][dd];
    long off = ((long)b * 4 + i) * 1024 + (long)h * d + dd;
    if (obf) outb[off] = f2b(o);
    else outf[off] = o;
  }
}

// ---------------- LayerNorm width 1024, f32 + bf16 outputs -----------------
__global__ __launch_bounds__(256) void k_ln1024(const float* __restrict__ in,
                                                const float* __restrict__ gg,
                                                const float* __restrict__ bb,
                                                float* __restrict__ outf,
                                                unsigned short* __restrict__ outb) {
  const long r = blockIdx.x;
  const int tid = threadIdx.x;
  __shared__ float red[4];
  const float* ip = in + r * 1024;
  float v[4];
#pragma unroll
  for (int i = 0; i < 4; ++i) v[i] = ip[tid + i * 256];
  float m = bsum(v[0] + v[1] + v[2] + v[3], red) * (1.f / 1024.f);
  float q = 0.f;
#pragma unroll
  for (int i = 0; i < 4; ++i) q += (v[i] - m) * (v[i] - m);
  float rstd = rsqrtf(bsum(q, red) * (1.f / 1024.f) + 1e-5f);
#pragma unroll
  for (int i = 0; i < 4; ++i) {
    int cidx = tid + i * 256;
    float o = (v[i] - m) * rstd * gg[cidx] + bb[cidx];
    outf[r * 1024 + cidx] = o;
    outb[r * 1024 + cidx] = f2b(o);
  }
}

// ---------------- DMIN LN + sigmoid gate -----------------------------------
__global__ __launch_bounds__(256) void k_dmin(const float* __restrict__ zin,
                                              const float* __restrict__ ori,
                                              const float* __restrict__ gg,
                                              const float* __restrict__ bb,
                                              float* __restrict__ y2) {
  const long r = blockIdx.x;
  const int tid = threadIdx.x;
  __shared__ float red[4];
  const float* ip = zin + r * 1024;
  float v[4];
#pragma unroll
  for (int i = 0; i < 4; ++i) v[i] = ip[tid + i * 256];
  float m = bsum(v[0] + v[1] + v[2] + v[3], red) * (1.f / 1024.f);
  float q = 0.f;
#pragma unroll
  for (int i = 0; i < 4; ++i) q += (v[i] - m) * (v[i] - m);
  float rstd = rsqrtf(bsum(q, red) * (1.f / 1024.f) + 1e-5f);
#pragma unroll
  for (int i = 0; i < 4; ++i) {
    int cidx = tid + i * 256;
    float ln = (v[i] - m) * rstd * gg[cidx] + bb[cidx];
    y2[r * 1024 + cidx] = ori[r * 1024 + cidx] * (1.f / (1.f + expf(-ln)));
  }
}

// ---------------- pwconv (bag 4 -> 1, k=3, pad 1) --------------------------
__global__ __launch_bounds__(256) void k_pw(const float* __restrict__ y2,
                                            const float* __restrict__ pw,
                                            const float* __restrict__ pb,
                                            float* __restrict__ xfer) {
  const int b = blockIdx.x;
  __shared__ float w[12];
  if (threadIdx.x < 12) w[threadIdx.x] = pw[threadIdx.x];
  __syncthreads();
  const float bias = pb[0];
  for (int e = threadIdx.x; e < 1024; e += 256) {
    float acc = bias;
#pragma unroll
    for (int c = 0; c < 4; ++c) {
      const float* yr = y2 + (long)b * 4096 + (long)c * 1024;
      if (e > 0) acc = fmaf(yr[e - 1], w[c * 3 + 0], acc);
      acc = fmaf(yr[e], w[c * 3 + 1], acc);
      if (e < 1023) acc = fmaf(yr[e + 1], w[c * 3 + 2], acc);
    }
    xfer[(long)b * 1024 + e] = acc;
  }
}

// ---------------- final fc: [1024] -> [7] ----------------------------------
__global__ __launch_bounds__(256) void k_fc(const float* __restrict__ xf,
                                            const float* __restrict__ fw,
                                            const float* __restrict__ fb,
                                            float* __restrict__ out) {
  const int b = blockIdx.x, tid = threadIdx.x;
  float acc[7] = {0.f, 0.f, 0.f, 0.f, 0.f, 0.f, 0.f};
  for (int e = tid; e < 1024; e += 256) {
    float xv = xf[(long)b * 1024 + e];
#pragma unroll
    for (int j = 0; j < 7; ++j) acc[j] = fmaf(xv, fw[j * 1024 + e], acc[j]);
  }
  __shared__ float red[4][7];
#pragma unroll
  for (int j = 0; j < 7; ++j) {
    float v = acc[j];
#pragma unroll
    for (int off = 32; off; off >>= 1) v += __shfl_down(v, off, 64);
    if ((tid & 63) == 0) red[tid >> 6][j] = v;
  }
  __syncthreads();
  if (tid < 7)
    out[(long)b * 7 + tid] =
        red[0][tid] + red[1][tid] + red[2][tid] + red[3][tid] + fb[tid];
}

// LSTM wavefront stages: cells (t,l); stage 3 split so z live-set <= 3 slabs.
// Ordering verified against h/c in-place dependency graph.
static const int ST[8][3][2] = {
    {{0, 0}, {0, 0}, {0, 0}},
    {{1, 0}, {0, 1}, {0, 0}},
    {{2, 0}, {1, 1}, {0, 2}},
    {{1, 2}, {0, 3}, {0, 0}},
    {{3, 0}, {2, 1}, {0, 0}},
    {{3, 1}, {2, 2}, {1, 3}},
    {{3, 2}, {2, 3}, {0, 0}},
    {{3, 3}, {0, 0}, {0, 0}},
};
static const int NC[8] = {1, 2, 3, 2, 2, 3, 2, 1};

// ===========================================================================
extern "C" void kernel_launch(void* const* d_in, const int* in_sizes, int n_in,
                              void* d_out, int out_size, void* d_ws,
                              size_t ws_size, hipStream_t stream) {
  const float* x = (const float*)d_in[0];
  const float* nv1 = (const float*)d_in[1];
  const float* nv2 = (const float*)d_in[2];
  const float* sc_w = (const float*)d_in[3];
  const float* sc_b = (const float*)d_in[4];
  const float* mp_w = (const float*)d_in[5];
  const float* mp_b = (const float*)d_in[6];
  const float* ec_w = (const float*)d_in[7];
  const float* ec_b = (const float*)d_in[8];
  const float* gbl_w = (const float*)d_in[9];
  const float* gbl_b = (const float*)d_in[10];
  const float* gbln_g = (const float*)d_in[11];
  const float* gbln_b = (const float*)d_in[12];
  const float* lstm_W = (const float*)d_in[13];
  const float* lstm_Wb = (const float*)d_in[14];
  const float* lstm_U = (const float*)d_in[15];
  const float* lstm_Ub = (const float*)d_in[16];
  const float* mha_in_w = (const float*)d_in[17];
  const float* mha_in_b = (const float*)d_in[18];
  const float* mha_out_w = (const float*)d_in[19];
  const float* mha_out_b = (const float*)d_in[20];
  const float* ln1_g = (const float*)d_in[21];
  const float* ln1_b = (const float*)d_in[22];
  const float* qkv_w = (const float*)d_in[23];
  const float* dmin_g = (const float*)d_in[24];
  const float* dmin_b = (const float*)d_in[25];
  const float* pw_w = (const float*)d_in[26];
  const float* pw_b = (const float*)d_in[27];
  const float* fc_w = (const float*)d_in[28];
  const float* fc_b = (const float*)d_in[29];

  char* wsb = (char*)d_ws;
  float* out = (float*)d_out;
  float* xfer = out + 1024 * 7;

  // persistent (LSTM phase)
  unsigned short* xgbf = (unsigned short*)(wsb + 0);
  unsigned short* gwbf = (unsigned short*)(wsb + 4194304);
  unsigned short* Wbf = (unsigned short*)(wsb + 8388608);
  unsigned short* Ubf = (unsigned short*)(wsb + 29360128);
  unsigned short* hbf = (unsigned short*)(wsb + 50331648);
  float* cst = (float*)(wsb + 58720256);
  unsigned short* zbf = (unsigned short*)(wsb + 75497472);  // 3 slabs
  unsigned short* ylbf = (unsigned short*)(wsb + 106954752);
  // graph scratch (aliases z region, dies before LSTM)
  unsigned short* xbf = (unsigned short*)(wsb + 75497472);
  unsigned short* aBf = (unsigned short*)(wsb + 79691776);
  unsigned short* gblbf = (unsigned short*)(wsb + 80216064);
  float* wY = (float*)(wsb + 80740352);
  unsigned short* oebf = (unsigned short*)(wsb + 89128960);
  float* wCF = (float*)(wsb + 93323264);
  // post-LSTM (aliases everything except ylbf until it's consumed)
  unsigned short* m1w = (unsigned short*)(wsb + 0);
  float* qkv = (float*)(wsb + 6291456);
  unsigned short* attb = (unsigned short*)(wsb + 56623104);
  float* attf = (float*)(wsb + 56623104);
  unsigned short* m2w = (unsigned short*)(wsb + 73400320);
  float* mhay = (float*)(wsb + 75497472);
  float* orif = (float*)(wsb + 92274688);
  unsigned short* orib = (unsigned short*)(wsb + 109051904);
  unsigned short* qw2 = (unsigned short*)(wsb + 0);
  float* y2 = (float*)(wsb + 75497472);

  // zero h_bf + c (contiguous)
  hipMemsetAsync(wsb + 50331648, 0, 25165824, stream);

  // ---- convert static operands to bf16 ----
  k_cvt<<<1024, 256, 0, stream>>>(x, xbf);
  k_cvt<<<5120, 256, 0, stream>>>(lstm_W, Wbf);
  k_cvt<<<5120, 256, 0, stream>>>(lstm_U, Ubf);
  k_cvt<<<128, 256, 0, stream>>>(gbl_w, gblbf);

  // ---- graph block ----
  k_adj<<<512, 256, 0, stream>>>(nv1, nv2, aBf);
  k_coef<<<1, 64, 0, stream>>>(mp_w, mp_b, sc_w, sc_b, wCF);
  k_bgemm<<<dim3(32, 4), 256, 0, stream>>>(xbf, 512, aBf, 512, nullptr, wY,
                                           512, 512);
  k_oe<<<dim3(1024, 2), 256, 0, stream>>>(x, wY, wCF, ec_w, ec_b, oebf);
  k_bgemm<<<dim3(32, 4), 256, 0, stream>>>(oebf, 512, gblbf, 512, gbl_b, wY,
                                           512, 512);
  k_lngw<<<4096, 256, 0, stream>>>(x, wY, gbln_g, gbln_b, xgbf, gwbf);

  // ---- bidirectional 4-layer LSTM, wavefront over (t,l) ----
  for (int s = 0; s < 8; ++s) {
    const int nc = NC[s];
    LStage lp;
    GStage gp;
    for (int ci = 0; ci < nc; ++ci) {
      const int t = ST[s][ci][0], l = ST[s][ci][1];
      for (int dir = 0; dir < 2; ++dir) {
        const int sl = ci * 2 + dir;
        if (l == 0) {
          lp.a0[sl] = xgbf + (dir ? (3 - t) : t) * 512;
          lp.lda0[sl] = 2048;
        } else {
          lp.a0[sl] = hbf + (long)(dir * 4 + l - 1) * 524288;
          lp.lda0[sl] = 512;
        }
        lp.a2[sl] = hbf + (long)(dir * 4 + l) * 524288;
        lp.w[sl] = Wbf + (long)(dir * 4 + l) * 1310720;
        lp.u[sl] = Ubf + (long)(dir * 4 + l) * 1310720;
        unsigned short* zslice = zbf + (long)ci * 5242880 + (long)dir * 2621440;
        lp.zo[sl] = zslice;
        gp.z[sl] = zslice;
        gp.tt[sl] = t;
        gp.ll[sl] = l;
      }
    }
    k_lgemm<<<dim3(8, 20, nc * 2), 256, 0, stream>>>(lp);
    k_gates<<<dim3(2048, nc * 2), 256, 0, stream>>>(gp, lstm_Wb, lstm_Ub, gwbf,
                                                    hbf, cst, ylbf);
  }

  // ---- MHA (4 heads, d=256) ----
  k_cvt<<<1536, 256, 0, stream>>>(mha_in_w, m1w);
  k_bgemm<<<dim3(32, 24), 256, 0, stream>>>(ylbf, 1024, m1w, 1024, mha_in_b,
                                            qkv, 3072, 1024);
  k_attn<<<dim3(1024, 4), 256, 0, stream>>>(qkv, attb, nullptr, 256, 1.f / 16.f, 1);
  k_cvt<<<512, 256, 0, stream>>>(mha_out_w, m2w);
  k_bgemm<<<dim3(32, 8), 256, 0, stream>>>(attb, 1024, m2w, 1024, mha_out_b,
                                           mhay, 1024, 1024);
  k_ln1024<<<4096, 256, 0, stream>>>(mhay, ln1_g, ln1_b, orif, orib);

  // ---- MIL self-attention fusion (8 heads, d=128) ----
  k_cvt<<<1536, 256, 0, stream>>>(qkv_w, qw2);
  k_bgemm<<<dim3(32, 24), 256, 0, stream>>>(orib, 1024, qw2, 1024, nullptr,
                                            qkv, 3072, 1024);
  k_attn<<<dim3(1024, 8), 256, 0, stream>>>(qkv, nullptr, attf, 128,
                                            0.08838834764831845f, 0);
  k_dmin<<<4096, 256, 0, stream>>>(attf, orif, dmin_g, dmin_b, y2);

  // ---- pwconv + fc ----
  k_pw<<<1024, 256, 0, stream>>>(y2, pw_w, pw_b, xfer);
  k_fc<<<1024, 256, 0, stream>>>(xfer, fc_w, fc_b, out);
}

// Round 6
// 859.571 us; speedup vs baseline: 4.6566x; 1.0857x over previous
//
#include <hip/hip_runtime.h>

#define DEV __device__ __forceinline__

typedef __attribute__((ext_vector_type(8))) short bf16x8;
typedef __attribute__((ext_vector_type(8))) unsigned short u16x8;
typedef __attribute__((ext_vector_type(4))) float f32x4;

DEV unsigned short f2b(float f) {
  union { float f; unsigned u; } v;
  v.f = f;
  unsigned r = v.u + 0x7FFFu + ((v.u >> 16) & 1u);
  return (unsigned short)(r >> 16);
}
DEV float b2f(unsigned short u) {
  union { unsigned u; float f; } v;
  v.u = ((unsigned)u) << 16;
  return v.f;
}
DEV float sigmoidf(float x) { return 1.f / (1.f + expf(-x)); }

// async global->LDS, 16B per lane; LDS dest = wave-uniform base + lane*16
#define GL16(gp, lp)                                                        \
  __builtin_amdgcn_global_load_lds(                                         \
      (const __attribute__((address_space(1))) unsigned int*)(gp),          \
      (__attribute__((address_space(3))) unsigned int*)(lp), 16, 0, 0)

// ---------------- block reduce helpers (blockDim == 256) ----------------
DEV float bsum(float v, float* red) {
#pragma unroll
  for (int off = 32; off; off >>= 1) v += __shfl_down(v, off, 64);
  int tid = threadIdx.x;
  __syncthreads();
  if ((tid & 63) == 0) red[tid >> 6] = v;
  __syncthreads();
  return red[0] + red[1] + red[2] + red[3];
}
DEV float bmax(float v, float* red) {
#pragma unroll
  for (int off = 32; off; off >>= 1) v = fmaxf(v, __shfl_down(v, off, 64));
  int tid = threadIdx.x;
  __syncthreads();
  if ((tid & 63) == 0) red[tid >> 6] = v;
  __syncthreads();
  return fmaxf(fmaxf(red[0], red[1]), fmaxf(red[2], red[3]));
}

// ---------------- f32 -> bf16 bulk convert (n = grid*2048 elems) -----------
__global__ __launch_bounds__(256) void k_cvt(const float* __restrict__ in,
                                             unsigned short* __restrict__ out) {
  long i = ((long)blockIdx.x * 256 + threadIdx.x) * 8;
  float4 a = *(const float4*)(in + i);
  float4 b = *(const float4*)(in + i + 4);
  u16x8 o;
  o[0] = f2b(a.x); o[1] = f2b(a.y); o[2] = f2b(a.z); o[3] = f2b(a.w);
  o[4] = f2b(b.x); o[5] = f2b(b.y); o[6] = f2b(b.z); o[7] = f2b(b.w);
  *(u16x8*)(out + i) = o;
}

// ---------------- adjacency: a = (softmax(relu(nv1@nv2)) + I)/2, bf16 ------
__global__ __launch_bounds__(256) void k_adj(const float* __restrict__ nv1,
                                             const float* __restrict__ nv2,
                                             unsigned short* __restrict__ a) {
  const int v = blockIdx.x, tid = threadIdx.x;
  __shared__ float n1[32];
  __shared__ float red[4];
  if (tid < 32) n1[tid] = nv1[v * 32 + tid];
  __syncthreads();
  float r0, r1;
  {
    float s = 0.f;
#pragma unroll 8
    for (int k = 0; k < 32; ++k) s += n1[k] * nv2[k * 512 + tid];
    r0 = fmaxf(s, 0.f);
  }
  {
    float s = 0.f;
#pragma unroll 8
    for (int k = 0; k < 32; ++k) s += n1[k] * nv2[k * 512 + tid + 256];
    r1 = fmaxf(s, 0.f);
  }
  float mx = bmax(fmaxf(r0, r1), red);
  float e0 = expf(r0 - mx), e1 = expf(r1 - mx);
  float s = bsum(e0 + e1, red);
  float inv = 1.f / s;
  int w0 = tid, w1 = tid + 256;
  a[(long)v * 512 + w0] = f2b((e0 * inv + (w0 == v ? 1.f : 0.f)) * 0.5f);
  a[(long)v * 512 + w1] = f2b((e1 * inv + (w1 == v ? 1.f : 0.f)) * 0.5f);
}

// ---------------- fold start_conv + mixprop + 1x1 mlp into coef vectors ----
__global__ void k_coef(const float* __restrict__ mp_w, const float* __restrict__ mp_b,
                       const float* __restrict__ sc_w, const float* __restrict__ sc_b,
                       float* __restrict__ cf) {
  int o = threadIdx.x;
  if (o < 32) {
    float A = 0.f, Bv = 0.f, Cv = 0.f;
    for (int cc = 0; cc < 32; ++cc) {
      float m1 = mp_w[o * 64 + cc], m2 = mp_w[o * 64 + 32 + cc];
      float sw = sc_w[cc], sb = sc_b[cc];
      A += (m1 + 0.7f * m2) * sw;
      Bv += 0.3f * m2 * sw;
      Cv += (m1 + m2) * sb;
    }
    cf[o] = A;
    cf[32 + o] = Bv;
    cf[64 + o] = Cv + mp_b[o];
  }
}

// ---------------- 2-phase pipelined MFMA GEMM core -------------------------
// BM=BN=128, BK=32, 4 waves (2x2), double-buffered LDS (2 x 16 KB).
// Per step: stage(t+1) || ds_read(cur) + 16 MFMA; counted drain at step end.
// 64B LDS rows -> fragment reads bank-uniform (quad = 4*(lr&1)+lg), no swizzle.
DEV void gemm_pipe(const unsigned short* A0, long lda0,
                   const unsigned short* B0, long ldb0,
                   const unsigned short* A1, long lda1,
                   const unsigned short* B1, long ldb1,
                   int sps, int dual, int bm, int bn, int tid,
                   unsigned short* lds, f32x4 (&acc)[4][4]) {
  const int lane = tid & 63, wave = tid >> 6;
  const int wr = wave >> 1, wc = wave & 1;
  const int lr = lane & 15, lg = lane >> 4;
  const int srow = wave * 16 + (lane >> 2);   // staged row (i-round adds 64)
  const int scx = (lane & 3) * 8;             // 16B chunk within 64B row
  const unsigned short* pa0 = A0 + (long)(bm * 128 + srow) * lda0 + scx;
  const unsigned short* pa1 = A1 + (long)(bm * 128 + srow) * lda1 + scx;
  const unsigned short* pb0 = B0 + (long)(bn * 128 + srow) * ldb0 + scx;
  const unsigned short* pb1 = B1 + (long)(bn * 128 + srow) * ldb1 + scx;
  const int aoff = (wr * 64 + lr) * 32 + lg * 8;
  const int boff = 4096 + (wc * 64 + lr) * 32 + lg * 8;
  const int tot = dual ? sps * 2 : sps;

  auto stage = [&](int t, int buf) {
    const int seg = (dual && t >= sps) ? 1 : 0;
    const long k0 = (long)(t - seg * sps) * 32;
    const unsigned short* ap = (seg ? pa1 : pa0) + k0;
    const unsigned short* bp = (seg ? pb1 : pb0) + k0;
    const long la = seg ? lda1 : lda0;
    const long lb = seg ? ldb1 : ldb0;
    unsigned short* d = lds + buf * 8192;
    GL16(ap, d + wave * 512);
    GL16(ap + 64 * la, d + 2048 + wave * 512);
    GL16(bp, d + 4096 + wave * 512);
    GL16(bp + 64 * lb, d + 6144 + wave * 512);
  };

  stage(0, 0);
  asm volatile("s_waitcnt vmcnt(0)" ::: "memory");
  __builtin_amdgcn_s_barrier();
  int cur = 0;
  for (int t = 0; t < tot; ++t) {
    if (t + 1 < tot) stage(t + 1, cur ^ 1);
    const unsigned short* base = lds + cur * 8192;
    bf16x8 af[4], bq[4];
#pragma unroll
    for (int m = 0; m < 4; ++m) af[m] = *(const bf16x8*)&base[aoff + m * 512];
#pragma unroll
    for (int n = 0; n < 4; ++n) bq[n] = *(const bf16x8*)&base[boff + n * 512];
    __builtin_amdgcn_s_setprio(1);
#pragma unroll
    for (int m = 0; m < 4; ++m)
#pragma unroll
      for (int n = 0; n < 4; ++n)
        acc[m][n] = __builtin_amdgcn_mfma_f32_16x16x32_bf16(af[m], bq[n],
                                                            acc[m][n], 0, 0, 0);
    __builtin_amdgcn_s_setprio(0);
    asm volatile("s_waitcnt vmcnt(0)" ::: "memory");
    __builtin_amdgcn_sched_barrier(0);
    __builtin_amdgcn_s_barrier();
    cur ^= 1;
  }
}

// ---------------- generic bf16 NT GEMM, f32 out (+bias) --------------------
__global__ __launch_bounds__(256) void k_bgemm(
    const unsigned short* __restrict__ A, long lda,
    const unsigned short* __restrict__ B, long ldb,
    const float* __restrict__ bias, float* __restrict__ C, long ldc, int K) {
  __shared__ unsigned short lds[16384];
  f32x4 acc[4][4];
#pragma unroll
  for (int m = 0; m < 4; ++m)
#pragma unroll
    for (int n = 0; n < 4; ++n) acc[m][n] = (f32x4){0.f, 0.f, 0.f, 0.f};
  gemm_pipe(A, lda, B, ldb, A, lda, B, ldb, K / 32, 0, blockIdx.x, blockIdx.y,
            threadIdx.x, lds, acc);
  const int lane = threadIdx.x & 63, wave = threadIdx.x >> 6;
  const int wr = wave >> 1, wc = wave & 1, lr = lane & 15, lg = lane >> 4;
  const long crow0 = (long)blockIdx.x * 128 + wr * 64;
  const int col0 = blockIdx.y * 128 + wc * 64;
#pragma unroll
  for (int n = 0; n < 4; ++n) {
    const int col = col0 + n * 16 + lr;
    const float bv = bias ? bias[col] : 0.f;
#pragma unroll
    for (int m = 0; m < 4; ++m) {
      const long rbase = (crow0 + m * 16 + lg * 4) * ldc + col;
#pragma unroll
      for (int j = 0; j < 4; ++j) C[rbase + (long)j * ldc] = acc[m][n][j] + bv;
    }
  }
}

// ---------------- LSTM stage GEMM: z = a0@W^T + a2@U^T, bf16 out -----------
struct LStage {
  const unsigned short* a0[6];
  const unsigned short* a2[6];
  const unsigned short* w[6];
  const unsigned short* u[6];
  unsigned short* zo[6];
  long lda0[6];
};

__global__ __launch_bounds__(256) void k_lgemm(LStage p) {
  __shared__ unsigned short lds[16384];
  const int z = blockIdx.z;
  f32x4 acc[4][4];
#pragma unroll
  for (int m = 0; m < 4; ++m)
#pragma unroll
    for (int n = 0; n < 4; ++n) acc[m][n] = (f32x4){0.f, 0.f, 0.f, 0.f};
  gemm_pipe(p.a0[z], p.lda0[z], p.w[z], 512, p.a2[z], 512, p.u[z], 512, 16, 1,
            blockIdx.x, blockIdx.y, threadIdx.x, lds, acc);
  unsigned short* zo = p.zo[z];
  const int lane = threadIdx.x & 63, wave = threadIdx.x >> 6;
  const int wr = wave >> 1, wc = wave & 1, lr = lane & 15, lg = lane >> 4;
  const long crow0 = (long)blockIdx.x * 128 + wr * 64;
  const int col0 = blockIdx.y * 128 + wc * 64;
#pragma unroll
  for (int n = 0; n < 4; ++n) {
    const int col = col0 + n * 16 + lr;
#pragma unroll
    for (int m = 0; m < 4; ++m) {
      const long rbase = (crow0 + m * 16 + lg * 4) * 2560 + col;
#pragma unroll
      for (int j = 0; j < 4; ++j) zo[rbase + (long)j * 2560] = f2b(acc[m][n][j]);
    }
  }
}

// ---------------- LSTM gates (per wavefront stage) -------------------------
struct GStage {
  const unsigned short* z[6];
  int tt[6];
  int ll[6];
};

__global__ __launch_bounds__(256) void k_gates(
    GStage g, const float* __restrict__ Wb, const float* __restrict__ Ub,
    const unsigned short* __restrict__ gwbf, unsigned short* __restrict__ hbf,
    float* __restrict__ c, unsigned short* __restrict__ ylbf) {
  const int s = blockIdx.y, dir = s & 1;
  const int t = g.tt[s], l = g.ll[s];
  const unsigned short* zp = g.z[s];
  const int idx = blockIdx.x * 256 + threadIdx.x;
  const int b = idx >> 9, o = idx & 511;
  const long boff = (long)(dir * 4 + l) * 2560 + o;
  const long zb = (long)b * 2560 + o;
  float zi = b2f(zp[zb]) + Wb[boff] + Ub[boff];
  float zf = b2f(zp[zb + 512]) + Wb[boff + 512] + Ub[boff + 512];
  float zoo = b2f(zp[zb + 1024]) + Wb[boff + 1024] + Ub[boff + 1024];
  float zc = b2f(zp[zb + 1536]) + Wb[boff + 1536] + Ub[boff + 1536];
  float zs = b2f(zp[zb + 2048]) + Wb[boff + 2048] + Ub[boff + 2048];
  const int tok = dir ? 3 - t : t;
  float dw = b2f(gwbf[(long)b * 2048 + tok * 512 + o]);
  const long hc = ((long)(dir * 4 + l) * 1024 + b) * 512 + o;
  float i_t = sigmoidf(zi), f_t = sigmoidf(zf), o_t = sigmoidf(zoo);
  float ch = tanhf(zc);
  float s_t = sigmoidf(zs) * dw;
  float cn = f_t * c[hc] + i_t * ch * s_t;
  float hn = o_t * tanhf(cn);
  c[hc] = cn;
  hbf[hc] = f2b(hn);
  if (l == 3) ylbf[(long)b * 4096 + tok * 1024 + dir * 512 + o] = f2b(hn);
}

// ---------------- fused gelu(A*x+B*y+C) -> end_conv einsum, bf16 out -------
__global__ __launch_bounds__(256) void k_oe(const float* __restrict__ x,
                                            const float* __restrict__ yg,
                                            const float* __restrict__ cf,
                                            const float* __restrict__ ec_w,
                                            const float* __restrict__ ec_b,
                                            unsigned short* __restrict__ oe) {
  const int b = blockIdx.x;
  const int v = blockIdx.y * 256 + threadIdx.x;
  __shared__ float ecs[512];
  __shared__ float cfs[96];
  __shared__ float ebs[4];
  if (threadIdx.x < 96) cfs[threadIdx.x] = cf[threadIdx.x];
  if (threadIdx.x < 4) ebs[threadIdx.x] = ec_b[threadIdx.x];
  for (int i = threadIdx.x; i < 512; i += 256) ecs[i] = ec_w[i];
  __syncthreads();
  float xl[4], yl[4];
#pragma unroll
  for (int l = 0; l < 4; ++l) {
    long off = ((long)b * 4 + l) * 512 + v;
    xl[l] = x[off];
    yl[l] = yg[off];
  }
  float o0 = ebs[0], o1 = ebs[1], o2 = ebs[2], o3 = ebs[3];
  for (int cc = 0; cc < 32; ++cc) {
    float A = cfs[cc], Bv = cfs[32 + cc], Cv = cfs[64 + cc];
#pragma unroll
    for (int l = 0; l < 4; ++l) {
      float u = fmaf(A, xl[l], fmaf(Bv, yl[l], Cv));
      float gu = 0.5f * u * (1.f + erff(u * 0.70710678118654752f));
      o0 = fmaf(ecs[(0 * 32 + cc) * 4 + l], gu, o0);
      o1 = fmaf(ecs[(1 * 32 + cc) * 4 + l], gu, o1);
      o2 = fmaf(ecs[(2 * 32 + cc) * 4 + l], gu, o2);
      o3 = fmaf(ecs[(3 * 32 + cc) * 4 + l], gu, o3);
    }
  }
  oe[((long)b * 4 + 0) * 512 + v] = f2b(o0);
  oe[((long)b * 4 + 1) * 512 + v] = f2b(o1);
  oe[((long)b * 4 + 2) * 512 + v] = f2b(o2);
  oe[((long)b * 4 + 3) * 512 + v] = f2b(o3);
}

// ---------------- LN(x+g) then softmax -> xg_bf, gw_bf ---------------------
__global__ __launch_bounds__(256) void k_lngw(const float* __restrict__ x,
                                              const float* __restrict__ g,
                                              const float* __restrict__ gg,
                                              const float* __restrict__ gb,
                                              unsigned short* __restrict__ xg,
                                              unsigned short* __restrict__ gw) {
  const long r = blockIdx.x;
  const int tid = threadIdx.x;
  __shared__ float red[4];
  const float* xp = x + r * 512;
  const float* gp = g + r * 512;
  float a0 = xp[tid] + gp[tid];
  float a1 = xp[tid + 256] + gp[tid + 256];
  float m = bsum(a0 + a1, red) * (1.f / 512.f);
  float q = (a0 - m) * (a0 - m) + (a1 - m) * (a1 - m);
  float var = bsum(q, red) * (1.f / 512.f);
  float rstd = rsqrtf(var + 1e-5f);
  float v0 = (a0 - m) * rstd * gg[tid] + gb[tid];
  float v1 = (a1 - m) * rstd * gg[tid + 256] + gb[tid + 256];
  xg[r * 512 + tid] = f2b(v0);
  xg[r * 512 + tid + 256] = f2b(v1);
  float mx = bmax(fmaxf(v0, v1), red);
  float e0 = expf(v0 - mx), e1 = expf(v1 - mx);
  float s = bsum(e0 + e1, red);
  float inv = 1.f / s;
  gw[r * 512 + tid] = f2b(e0 * inv);
  gw[r * 512 + tid + 256] = f2b(e1 * inv);
}

// ---------------- tiny attention (N=4 tokens), block = (b, head) ------------
__global__ __launch_bounds__(256) void k_attn(const float* __restrict__ qkv,
                                              unsigned short* __restrict__ outb,
                                              float* __restrict__ outf, int d,
                                              float scale, int obf) {
  const int b = blockIdx.x, h = blockIdx.y;
  __shared__ float qs[4][256], ks[4][256], vs[4][256];
  __shared__ float sc[4][4];
  const int tid = threadIdx.x;
  for (int tok = 0; tok < 4; ++tok) {
    const float* base = qkv + ((long)b * 4 + tok) * 3072 + h * d;
    for (int j = tid; j < d; j += 256) {
      qs[tok][j] = base[j];
      ks[tok][j] = base[1024 + j];
      vs[tok][j] = base[2048 + j];
    }
  }
  __syncthreads();
  if (tid < 16) {
    int i = tid >> 2, j = tid & 3;
    float s = 0.f;
    for (int dd = 0; dd < d; ++dd) s += qs[i][dd] * ks[j][dd];
    sc[i][j] = s * scale;
  }
  __syncthreads();
  if (tid < 4) {
    float m = fmaxf(fmaxf(sc[tid][0], sc[tid][1]), fmaxf(sc[tid][2], sc[tid][3]));
    float e0 = expf(sc[tid][0] - m), e1 = expf(sc[tid][1] - m);
    float e2 = expf(sc[tid][2] - m), e3 = expf(sc[tid][3] - m);
    float inv = 1.f / (e0 + e1 + e2 + e3);
    sc[tid][0] = e0 * inv;
    sc[tid][1] = e1 * inv;
    sc[tid][2] = e2 * inv;
    sc[tid][3] = e3 * inv;
  }
  __syncthreads();
  for (int idx = tid; idx < 4 * d; idx += 256) {
    int i = idx / d, dd = idx - i * d;
    float o = sc[i][0] * vs[0][dd] + sc[i][1] * vs[1][dd] + sc[i][2] * vs[2][dd] +
              sc[i][3] * vs[3][dd];
    long off = ((long)b * 4 + i) * 1024 + (long)h * d + dd;
    if (obf) outb[off] = f2b(o);
    else outf[off] = o;
  }
}

// ---------------- LayerNorm width 1024, f32 + bf16 outputs -----------------
__global__ __launch_bounds__(256) void k_ln1024(const float* __restrict__ in,
                                                const float* __restrict__ gg,
                                                const float* __restrict__ bb,
                                                float* __restrict__ outf,
                                                unsigned short* __restrict__ outb) {
  const long r = blockIdx.x;
  const int tid = threadIdx.x;
  __shared__ float red[4];
  const float* ip = in + r * 1024;
  float v[4];
#pragma unroll
  for (int i = 0; i < 4; ++i) v[i] = ip[tid + i * 256];
  float m = bsum(v[0] + v[1] + v[2] + v[3], red) * (1.f / 1024.f);
  float q = 0.f;
#pragma unroll
  for (int i = 0; i < 4; ++i) q += (v[i] - m) * (v[i] - m);
  float rstd = rsqrtf(bsum(q, red) * (1.f / 1024.f) + 1e-5f);
#pragma unroll
  for (int i = 0; i < 4; ++i) {
    int cidx = tid + i * 256;
    float o = (v[i] - m) * rstd * gg[cidx] + bb[cidx];
    outf[r * 1024 + cidx] = o;
    outb[r * 1024 + cidx] = f2b(o);
  }
}

// ---------------- DMIN LN + sigmoid gate -----------------------------------
__global__ __launch_bounds__(256) void k_dmin(const float* __restrict__ zin,
                                              const float* __restrict__ ori,
                                              const float* __restrict__ gg,
                                              const float* __restrict__ bb,
                                              float* __restrict__ y2) {
  const long r = blockIdx.x;
  const int tid = threadIdx.x;
  __shared__ float red[4];
  const float* ip = zin + r * 1024;
  float v[4];
#pragma unroll
  for (int i = 0; i < 4; ++i) v[i] = ip[tid + i * 256];
  float m = bsum(v[0] + v[1] + v[2] + v[3], red) * (1.f / 1024.f);
  float q = 0.f;
#pragma unroll
  for (int i = 0; i < 4; ++i) q += (v[i] - m) * (v[i] - m);
  float rstd = rsqrtf(bsum(q, red) * (1.f / 1024.f) + 1e-5f);
#pragma unroll
  for (int i = 0; i < 4; ++i) {
    int cidx = tid + i * 256;
    float ln = (v[i] - m) * rstd * gg[cidx] + bb[cidx];
    y2[r * 1024 + cidx] = ori[r * 1024 + cidx] * (1.f / (1.f + expf(-ln)));
  }
}

// ---------------- pwconv (bag 4 -> 1, k=3, pad 1) --------------------------
__global__ __launch_bounds__(256) void k_pw(const float* __restrict__ y2,
                                            const float* __restrict__ pw,
                                            const float* __restrict__ pb,
                                            float* __restrict__ xfer) {
  const int b = blockIdx.x;
  __shared__ float w[12];
  if (threadIdx.x < 12) w[threadIdx.x] = pw[threadIdx.x];
  __syncthreads();
  const float bias = pb[0];
  for (int e = threadIdx.x; e < 1024; e += 256) {
    float acc = bias;
#pragma unroll
    for (int c = 0; c < 4; ++c) {
      const float* yr = y2 + (long)b * 4096 + (long)c * 1024;
      if (e > 0) acc = fmaf(yr[e - 1], w[c * 3 + 0], acc);
      acc = fmaf(yr[e], w[c * 3 + 1], acc);
      if (e < 1023) acc = fmaf(yr[e + 1], w[c * 3 + 2], acc);
    }
    xfer[(long)b * 1024 + e] = acc;
  }
}

// ---------------- final fc: [1024] -> [7] ----------------------------------
__global__ __launch_bounds__(256) void k_fc(const float* __restrict__ xf,
                                            const float* __restrict__ fw,
                                            const float* __restrict__ fb,
                                            float* __restrict__ out) {
  const int b = blockIdx.x, tid = threadIdx.x;
  float acc[7] = {0.f, 0.f, 0.f, 0.f, 0.f, 0.f, 0.f};
  for (int e = tid; e < 1024; e += 256) {
    float xv = xf[(long)b * 1024 + e];
#pragma unroll
    for (int j = 0; j < 7; ++j) acc[j] = fmaf(xv, fw[j * 1024 + e], acc[j]);
  }
  __shared__ float red[4][7];
#pragma unroll
  for (int j = 0; j < 7; ++j) {
    float v = acc[j];
#pragma unroll
    for (int off = 32; off; off >>= 1) v += __shfl_down(v, off, 64);
    if ((tid & 63) == 0) red[tid >> 6][j] = v;
  }
  __syncthreads();
  if (tid < 7)
    out[(long)b * 7 + tid] =
        red[0][tid] + red[1][tid] + red[2][tid] + red[3][tid] + fb[tid];
}

// LSTM wavefront stages: cells (t,l); stage 3 split so z live-set <= 3 slabs.
// Ordering verified against h/c in-place dependency graph.
static const int ST[8][3][2] = {
    {{0, 0}, {0, 0}, {0, 0}},
    {{1, 0}, {0, 1}, {0, 0}},
    {{2, 0}, {1, 1}, {0, 2}},
    {{1, 2}, {0, 3}, {0, 0}},
    {{3, 0}, {2, 1}, {0, 0}},
    {{3, 1}, {2, 2}, {1, 3}},
    {{3, 2}, {2, 3}, {0, 0}},
    {{3, 3}, {0, 0}, {0, 0}},
};
static const int NC[8] = {1, 2, 3, 2, 2, 3, 2, 1};

// ===========================================================================
extern "C" void kernel_launch(void* const* d_in, const int* in_sizes, int n_in,
                              void* d_out, int out_size, void* d_ws,
                              size_t ws_size, hipStream_t stream) {
  const float* x = (const float*)d_in[0];
  const float* nv1 = (const float*)d_in[1];
  const float* nv2 = (const float*)d_in[2];
  const float* sc_w = (const float*)d_in[3];
  const float* sc_b = (const float*)d_in[4];
  const float* mp_w = (const float*)d_in[5];
  const float* mp_b = (const float*)d_in[6];
  const float* ec_w = (const float*)d_in[7];
  const float* ec_b = (const float*)d_in[8];
  const float* gbl_w = (const float*)d_in[9];
  const float* gbl_b = (const float*)d_in[10];
  const float* gbln_g = (const float*)d_in[11];
  const float* gbln_b = (const float*)d_in[12];
  const float* lstm_W = (const float*)d_in[13];
  const float* lstm_Wb = (const float*)d_in[14];
  const float* lstm_U = (const float*)d_in[15];
  const float* lstm_Ub = (const float*)d_in[16];
  const float* mha_in_w = (const float*)d_in[17];
  const float* mha_in_b = (const float*)d_in[18];
  const float* mha_out_w = (const float*)d_in[19];
  const float* mha_out_b = (const float*)d_in[20];
  const float* ln1_g = (const float*)d_in[21];
  const float* ln1_b = (const float*)d_in[22];
  const float* qkv_w = (const float*)d_in[23];
  const float* dmin_g = (const float*)d_in[24];
  const float* dmin_b = (const float*)d_in[25];
  const float* pw_w = (const float*)d_in[26];
  const float* pw_b = (const float*)d_in[27];
  const float* fc_w = (const float*)d_in[28];
  const float* fc_b = (const float*)d_in[29];

  char* wsb = (char*)d_ws;
  float* out = (float*)d_out;
  float* xfer = out + 1024 * 7;

  // persistent (LSTM phase)
  unsigned short* xgbf = (unsigned short*)(wsb + 0);
  unsigned short* gwbf = (unsigned short*)(wsb + 4194304);
  unsigned short* Wbf = (unsigned short*)(wsb + 8388608);
  unsigned short* Ubf = (unsigned short*)(wsb + 29360128);
  unsigned short* hbf = (unsigned short*)(wsb + 50331648);
  float* cst = (float*)(wsb + 58720256);
  unsigned short* zbf = (unsigned short*)(wsb + 75497472);  // 3 slabs
  unsigned short* ylbf = (unsigned short*)(wsb + 106954752);
  // graph scratch (aliases z region, dies before LSTM)
  unsigned short* xbf = (unsigned short*)(wsb + 75497472);
  unsigned short* aBf = (unsigned short*)(wsb + 79691776);
  unsigned short* gblbf = (unsigned short*)(wsb + 80216064);
  float* wY = (float*)(wsb + 80740352);
  unsigned short* oebf = (unsigned short*)(wsb + 89128960);
  float* wCF = (float*)(wsb + 93323264);
  // post-LSTM (aliases everything except ylbf until it's consumed)
  unsigned short* m1w = (unsigned short*)(wsb + 0);
  float* qkv = (float*)(wsb + 6291456);
  unsigned short* attb = (unsigned short*)(wsb + 56623104);
  float* attf = (float*)(wsb + 56623104);
  unsigned short* m2w = (unsigned short*)(wsb + 73400320);
  float* mhay = (float*)(wsb + 75497472);
  float* orif = (float*)(wsb + 92274688);
  unsigned short* orib = (unsigned short*)(wsb + 109051904);
  unsigned short* qw2 = (unsigned short*)(wsb + 0);
  float* y2 = (float*)(wsb + 75497472);

  // zero h_bf + c (contiguous)
  hipMemsetAsync(wsb + 50331648, 0, 25165824, stream);

  // ---- convert static operands to bf16 ----
  k_cvt<<<1024, 256, 0, stream>>>(x, xbf);
  k_cvt<<<5120, 256, 0, stream>>>(lstm_W, Wbf);
  k_cvt<<<5120, 256, 0, stream>>>(lstm_U, Ubf);
  k_cvt<<<128, 256, 0, stream>>>(gbl_w, gblbf);

  // ---- graph block ----
  k_adj<<<512, 256, 0, stream>>>(nv1, nv2, aBf);
  k_coef<<<1, 64, 0, stream>>>(mp_w, mp_b, sc_w, sc_b, wCF);
  k_bgemm<<<dim3(32, 4), 256, 0, stream>>>(xbf, 512, aBf, 512, nullptr, wY,
                                           512, 512);
  k_oe<<<dim3(1024, 2), 256, 0, stream>>>(x, wY, wCF, ec_w, ec_b, oebf);
  k_bgemm<<<dim3(32, 4), 256, 0, stream>>>(oebf, 512, gblbf, 512, gbl_b, wY,
                                           512, 512);
  k_lngw<<<4096, 256, 0, stream>>>(x, wY, gbln_g, gbln_b, xgbf, gwbf);

  // ---- bidirectional 4-layer LSTM, wavefront over (t,l) ----
  for (int s = 0; s < 8; ++s) {
    const int nc = NC[s];
    LStage lp;
    GStage gp;
    for (int ci = 0; ci < nc; ++ci) {
      const int t = ST[s][ci][0], l = ST[s][ci][1];
      for (int dir = 0; dir < 2; ++dir) {
        const int sl = ci * 2 + dir;
        if (l == 0) {
          lp.a0[sl] = xgbf + (dir ? (3 - t) : t) * 512;
          lp.lda0[sl] = 2048;
        } else {
          lp.a0[sl] = hbf + (long)(dir * 4 + l - 1) * 524288;
          lp.lda0[sl] = 512;
        }
        lp.a2[sl] = hbf + (long)(dir * 4 + l) * 524288;
        lp.w[sl] = Wbf + (long)(dir * 4 + l) * 1310720;
        lp.u[sl] = Ubf + (long)(dir * 4 + l) * 1310720;
        unsigned short* zslice = zbf + (long)ci * 5242880 + (long)dir * 2621440;
        lp.zo[sl] = zslice;
        gp.z[sl] = zslice;
        gp.tt[sl] = t;
        gp.ll[sl] = l;
      }
    }
    k_lgemm<<<dim3(8, 20, nc * 2), 256, 0, stream>>>(lp);
    k_gates<<<dim3(2048, nc * 2), 256, 0, stream>>>(gp, lstm_Wb, lstm_Ub, gwbf,
                                                    hbf, cst, ylbf);
  }

  // ---- MHA (4 heads, d=256) ----
  k_cvt<<<1536, 256, 0, stream>>>(mha_in_w, m1w);
  k_bgemm<<<dim3(32, 24), 256, 0, stream>>>(ylbf, 1024, m1w, 1024, mha_in_b,
                                            qkv, 3072, 1024);
  k_attn<<<dim3(1024, 4), 256, 0, stream>>>(qkv, attb, nullptr, 256, 1.f / 16.f, 1);
  k_cvt<<<512, 256, 0, stream>>>(mha_out_w, m2w);
  k_bgemm<<<dim3(32, 8), 256, 0, stream>>>(attb, 1024, m2w, 1024, mha_out_b,
                                           mhay, 1024, 1024);
  k_ln1024<<<4096, 256, 0, stream>>>(mhay, ln1_g, ln1_b, orif, orib);

  // ---- MIL self-attention fusion (8 heads, d=128) ----
  k_cvt<<<1536, 256, 0, stream>>>(qkv_w, qw2);
  k_bgemm<<<dim3(32, 24), 256, 0, stream>>>(orib, 1024, qw2, 1024, nullptr,
                                            qkv, 3072, 1024);
  k_attn<<<dim3(1024, 8), 256, 0, stream>>>(qkv, nullptr, attf, 128,
                                            0.08838834764831845f, 0);
  k_dmin<<<4096, 256, 0, stream>>>(attf, orif, dmin_g, dmin_b, y2);

  // ---- pwconv + fc ----
  k_pw<<<1024, 256, 0, stream>>>(y2, pw_w, pw_b, xfer);
  k_fc<<<1024, 256, 0, stream>>>(xfer, fc_w, fc_b, out);
}